// Round 9
// baseline (2164.304 us; speedup 1.0000x reference)
//
#include <hip/hip_runtime.h>

#define DM    1000
#define DMP   1024
#define ED    2000
#define EDP   2048
#define NST   8
#define LSEQ  2048
#define NB    8
#define MTOT  16384     // NB*LSEQ
#define N1    4096      // gemm1 padded N (2*ED)
#define K1    1024      // gemm1 padded K
#define CHK   16        // scan chunks
#define CLEN  (LSEQ/CHK)

typedef unsigned short u16;
typedef __attribute__((ext_vector_type(4))) float f32x4;
typedef __attribute__((ext_vector_type(8))) short bf16x8;

__device__ __forceinline__ u16 f2bf(float f) {
    union { float f; unsigned u; } v; v.f = f;
    unsigned r = v.u + 0x7FFFu + ((v.u >> 16) & 1u);
    return (u16)(r >> 16);
}
__device__ __forceinline__ float bf2f(u16 h) {
    union { unsigned u; float f; } v; v.u = ((unsigned)h) << 16; return v.f;
}
__device__ __forceinline__ float siluf(float x) { return x / (1.f + __expf(-x)); }

// ---------------- mean over L of x ----------------
__global__ void meanx_kernel(const float* __restrict__ x, float* __restrict__ xm) {
    const int d = blockIdx.x * 256 + threadIdx.x;
    const int b = blockIdx.y;
    if (d >= DM) return;
    float s = 0.f;
    for (int l = 0; l < LSEQ; ++l) s += x[((size_t)b * LSEQ + l) * DM + d];
    xm[b * DMP + d] = s * (1.f / LSEQ);
}

// ---------------- RMSNorm -> bf16 padded (row = blockIdx.x) ----------------
__global__ void rms_kernel(const float* __restrict__ x, const float* __restrict__ w,
                           u16* __restrict__ xn) {
    const int row = blockIdx.x;
    const int tid = threadIdx.x;
    const float* xr = x + (size_t)row * DM;
    float ss = 0.f;
    for (int i = tid; i < DM; i += 256) { float v = xr[i]; ss = fmaf(v, v, ss); }
    #pragma unroll
    for (int o = 32; o > 0; o >>= 1) ss += __shfl_xor(ss, o);
    __shared__ float red[4];
    if ((tid & 63) == 0) red[tid >> 6] = ss;
    __syncthreads();
    float tot = red[0] + red[1] + red[2] + red[3];
    float sc = rsqrtf(tot * (1.f / DM) + 1e-5f);
    for (int i = tid; i < DMP; i += 256)
        xn[(size_t)row * DMP + i] = (i < DM) ? f2bf(xr[i] * sc * w[i]) : (u16)0;
}

// ---------------- weight packs (transpose to [N][K] bf16, zero-padded) --------
__global__ void packWt_kernel(const float* __restrict__ W, u16* __restrict__ Wt) {
    __shared__ float t[32][33];
    int nt = blockIdx.x * 32, kt = blockIdx.y * 32;
    int tx = threadIdx.x, ty = threadIdx.y;   // 32 x 8
    for (int j = 0; j < 32; j += 8) {
        int k = kt + ty + j, n = nt + tx;
        t[ty + j][tx] = (k < DM && n < 2 * ED) ? W[(size_t)k * (2 * ED) + n] : 0.f;
    }
    __syncthreads();
    for (int j = 0; j < 32; j += 8) {
        int n = nt + ty + j, k = kt + tx;
        Wt[(size_t)n * K1 + k] = f2bf(t[tx][ty + j]);
    }
}
// W_xproj [2000][79] -> WxT [128][2048]
__global__ void packWxT_kernel(const float* __restrict__ W, u16* __restrict__ WxT) {
    int gid = blockIdx.x * 256 + threadIdx.x;       // 128*2048
    int n = gid >> 11, k = gid & (EDP - 1);
    int c = (n < 63) ? n : ((n >= 64 && n < 80) ? n - 1 : -1);
    float v = (c >= 0 && k < ED) ? W[(size_t)k * 79 + c] : 0.f;
    WxT[gid] = f2bf(v);
}
// W_dt [63][2000] -> WdtT [2048][64]
__global__ void packWdtT_kernel(const float* __restrict__ W, u16* __restrict__ Wt) {
    int gid = blockIdx.x * 256 + threadIdx.x;       // 2048*64
    int n = gid >> 6, k = gid & 63;
    float v = (n < ED && k < 63) ? W[(size_t)k * ED + n] : 0.f;
    Wt[gid] = f2bf(v);
}

// ---------------- MFMA GEMM: C[M,N] = A[M,K] * Bt[N,K]^T, 128x128 tile ------
template<int MODE>
__global__ __launch_bounds__(256, 2)
void gemm_bt(const u16* __restrict__ A, const u16* __restrict__ Bt,
             int lda, int ldb, int ksteps,
             u16* __restrict__ o0, u16* __restrict__ o1,
             float* __restrict__ of, const float* __restrict__ bias) {
    __shared__ u16 As[128 * 32];
    __shared__ u16 Bs[128 * 32];
    const int tid = threadIdx.x;
    const int wv = tid >> 6, ln = tid & 63;
    const int mbase = blockIdx.y << 7, nbase = blockIdx.x << 7;
    const int wm = (wv >> 1) << 6, wn = (wv & 1) << 6;
    const int fr = ln & 15, fo = ln >> 4;

    f32x4 acc[4][4];
    #pragma unroll
    for (int i = 0; i < 4; ++i)
        #pragma unroll
        for (int j = 0; j < 4; ++j) acc[i][j] = (f32x4){0.f, 0.f, 0.f, 0.f};

    for (int ks = 0; ks < ksteps; ++ks) {
        const int kt = ks << 5;
        __syncthreads();
        #pragma unroll
        for (int i = 0; i < 2; ++i) {
            int c = (wv << 7) + (i << 6) + ln;            // chunk id 0..511
            const u16* ga = A + (size_t)(mbase + (c >> 2)) * lda + kt + ((c & 3) << 3);
            __builtin_amdgcn_global_load_lds(
                (const __attribute__((address_space(1))) void*)ga,
                (__attribute__((address_space(3))) void*)&As[((wv << 7) + (i << 6)) * 8],
                16, 0, 0);
            const u16* gb = Bt + (size_t)(nbase + (c >> 2)) * ldb + kt + ((c & 3) << 3);
            __builtin_amdgcn_global_load_lds(
                (const __attribute__((address_space(1))) void*)gb,
                (__attribute__((address_space(3))) void*)&Bs[((wv << 7) + (i << 6)) * 8],
                16, 0, 0);
        }
        asm volatile("s_waitcnt vmcnt(0)" ::: "memory");
        __syncthreads();

        bf16x8 af[4], bg[4];
        #pragma unroll
        for (int i = 0; i < 4; ++i) {
            af[i] = *(const bf16x8*)&As[((wm + (i << 4) + fr) << 5) + (fo << 3)];
            bg[i] = *(const bf16x8*)&Bs[((wn + (i << 4) + fr) << 5) + (fo << 3)];
        }
        #pragma unroll
        for (int i = 0; i < 4; ++i)
            #pragma unroll
            for (int j = 0; j < 4; ++j)
                acc[i][j] = __builtin_amdgcn_mfma_f32_16x16x32_bf16(af[i], bg[j], acc[i][j], 0, 0, 0);
    }

    #pragma unroll
    for (int i = 0; i < 4; ++i) {
        #pragma unroll
        for (int j = 0; j < 4; ++j) {
            int col = nbase + wn + (j << 4) + fr;
            #pragma unroll
            for (int r = 0; r < 4; ++r) {
                int row = mbase + wm + (i << 4) + (fo << 2) + r;
                float v = acc[i][j][r];
                if (MODE == 0) {
                    if (col < ED)            o0[(size_t)row * EDP + col] = f2bf(v);
                    else if (col < 2 * ED)   o1[(size_t)row * EDP + (col - ED)] = f2bf(siluf(v));
                } else if (MODE == 1) {
                    if (col < 64)            o0[(size_t)row * 64 + col] = f2bf(v);
                    else if (col < 80)       of[(size_t)row * 16 + (col - 64)] = v;
                } else {
                    if (col < ED) {
                        float s = v + bias[col];
                        float sp = (s > 20.f) ? s : log1pf(__expf(s));
                        o0[(size_t)row * EDP + col] = f2bf(sp);
                    }
                }
            }
        }
    }
}

// ---------------- depthwise causal conv (K=4) + bias + silu ----------------
__global__ void conv_kernel(const u16* __restrict__ xcr, const float* __restrict__ cw,
                            const float* __restrict__ cb, u16* __restrict__ xca) {
    const int ed = blockIdx.x * 256 + threadIdx.x;
    const int row = blockIdx.y;
    if (ed >= ED) { xca[(size_t)row * EDP + ed] = 0; return; }
    const int l = row & (LSEQ - 1);
    const float4 w = ((const float4*)cw)[ed];
    float s = cb[ed];
    const float wj[4] = {w.x, w.y, w.z, w.w};
    #pragma unroll
    for (int j = 0; j < 4; ++j) {
        int lj = l - 3 + j;
        if (lj >= 0) s = fmaf(wj[j], bf2f(xcr[(size_t)(row - 3 + j) * EDP + ed]), s);
    }
    xca[(size_t)row * EDP + ed] = f2bf(siluf(s));
}

// ---------------- selective scan pass 1: per-chunk local scan --------------
__global__ void scan1_kernel(const u16* __restrict__ dlt, const u16* __restrict__ xca,
                             const u16* __restrict__ zs, const float* __restrict__ bc,
                             const float* __restrict__ A_log, const float* __restrict__ Dp,
                             float* __restrict__ Pb, float* __restrict__ wb,
                             float* __restrict__ hlb, float* __restrict__ accb) {
    const int ed = blockIdx.x * 256 + threadIdx.x;
    const int b = blockIdx.y;
    const int c = blockIdx.z;
    const int edc = (ed < ED) ? ed : (ED - 1);
    float An[NST];
    #pragma unroll
    for (int n = 0; n < NST; ++n) An[n] = -__expf(A_log[edc * NST + n]);
    const float dpv = Dp[edc];
    float g[NST], cd[NST], w[NST];
    #pragma unroll
    for (int n = 0; n < NST; ++n) { g[n] = 0.f; cd[n] = 1.f; w[n] = 0.f; }
    float acc = 0.f;

    const size_t rbase = (size_t)b * LSEQ + (size_t)c * CLEN;
    const float4* bc4 = (const float4*)bc;
    size_t i0 = rbase * EDP + ed;
    float dv = bf2f(dlt[i0]), xv = bf2f(xca[i0]), zv = bf2f(zs[i0]);
    float4 q0 = bc4[rbase * 4 + 0], q1 = bc4[rbase * 4 + 1];
    float4 q2 = bc4[rbase * 4 + 2], q3 = bc4[rbase * 4 + 3];

    for (int l = 0; l < CLEN; ++l) {
        float dv2 = 0.f, xv2 = 0.f, zv2 = 0.f;
        float4 p0 = make_float4(0.f,0.f,0.f,0.f), p1 = p0, p2 = p0, p3 = p0;
        if (l + 1 < CLEN) {
            size_t i2 = (rbase + l + 1) * EDP + ed;
            dv2 = bf2f(dlt[i2]); xv2 = bf2f(xca[i2]); zv2 = bf2f(zs[i2]);
            p0 = bc4[(rbase + l + 1) * 4 + 0]; p1 = bc4[(rbase + l + 1) * 4 + 1];
            p2 = bc4[(rbase + l + 1) * 4 + 2]; p3 = bc4[(rbase + l + 1) * 4 + 3];
        }
        const float Bv[8] = {q0.x,q0.y,q0.z,q0.w,q1.x,q1.y,q1.z,q1.w};
        const float Cv[8] = {q2.x,q2.y,q2.z,q2.w,q3.x,q3.y,q3.z,q3.w};
        float dx = dv * xv;
        float yl = 0.f;
        #pragma unroll
        for (int n = 0; n < NST; ++n) {
            float dA = __expf(dv * An[n]);
            cd[n] *= dA;
            g[n] = fmaf(g[n], dA, dx * Bv[n]);
            yl = fmaf(g[n], Cv[n], yl);
            w[n] = fmaf(zv * Cv[n], cd[n], w[n]);
        }
        acc = fmaf(yl + dpv * xv, zv, acc);
        dv = dv2; xv = xv2; zv = zv2; q0 = p0; q1 = p1; q2 = p2; q3 = p3;
    }
    const size_t o = ((size_t)(b * CHK + c) * NST) * EDP + ed;
    #pragma unroll
    for (int n = 0; n < NST; ++n) {
        Pb [o + (size_t)n * EDP] = cd[n];
        wb [o + (size_t)n * EDP] = w[n];
        hlb[o + (size_t)n * EDP] = g[n];
    }
    accb[(size_t)(b * CHK + c) * EDP + ed] = acc;
}

// ---------------- selective scan pass 2: serial recombine over chunks ------
__global__ void scan2_kernel(const float* __restrict__ Pb, const float* __restrict__ wb,
                             const float* __restrict__ hlb, const float* __restrict__ accb,
                             float* __restrict__ sy) {
    const int ed = blockIdx.x * 256 + threadIdx.x;
    const int b = blockIdx.y;
    float h[NST];
    #pragma unroll
    for (int n = 0; n < NST; ++n) h[n] = 0.f;
    float acc = 0.f;
    #pragma unroll
    for (int c = 0; c < CHK; ++c) {
        const size_t o = ((size_t)(b * CHK + c) * NST) * EDP + ed;
        acc += accb[(size_t)(b * CHK + c) * EDP + ed];
        #pragma unroll
        for (int n = 0; n < NST; ++n) acc = fmaf(wb[o + (size_t)n * EDP], h[n], acc);
        #pragma unroll
        for (int n = 0; n < NST; ++n)
            h[n] = fmaf(Pb[o + (size_t)n * EDP], h[n], hlb[o + (size_t)n * EDP]);
    }
    if (ed < ED) sy[b * EDP + ed] = acc * (1.f / LSEQ);
}

// ---------------- e = xmean + sy @ W_outp ----------------
__global__ void e_kernel(const float* __restrict__ sy, const float* __restrict__ Wo,
                         const float* __restrict__ xm, float* __restrict__ e) {
    const int d = blockIdx.x * 256 + threadIdx.x;
    const int b = blockIdx.y;
    if (d >= DM) return;
    float s = 0.f;
    for (int k = 0; k < ED; ++k) s = fmaf(sy[b * EDP + k], Wo[(size_t)k * DM + d], s);
    e[b * DMP + d] = s + xm[b * DMP + d];
}

// ---------------- h = elu(tanh(e @ W_fc + b_fc)) ----------------
__global__ void fc_kernel(const float* __restrict__ e, const float* __restrict__ Wfc,
                          const float* __restrict__ bfc, float* __restrict__ out) {
    const int d = blockIdx.x * 256 + threadIdx.x;
    const int b = blockIdx.y;
    if (d >= DM) return;
    float s = bfc[d];
    for (int k = 0; k < DM; ++k) s = fmaf(e[b * DMP + k], Wfc[(size_t)k * DM + d], s);
    float t = tanhf(s);
    out[b * DM + d] = (t > 0.f) ? t : expm1f(t);
}

// ---------------- mu / sigma heads ----------------
__global__ void head_kernel(const float* __restrict__ hout, const float* __restrict__ Wmu,
                            const float* __restrict__ bmu, const float* __restrict__ Wsig,
                            const float* __restrict__ bsig, float* __restrict__ out) {
    const int o = threadIdx.x;   // 64
    const int b = blockIdx.x;
    float sm = bmu[o], sg = bsig[o];
    for (int k = 0; k < DM; ++k) {
        float hv = hout[b * DM + k];
        sm = fmaf(hv, Wmu[k * 64 + o], sm);
        sg = fmaf(hv, Wsig[k * 64 + o], sg);
    }
    out[8000 + b * 64 + o] = sm;
    float el = (sg > 0.f) ? sg : expm1f(sg);
    out[8512 + b * 64 + o] = el + 1.f + 1e-14f;
}

extern "C" void kernel_launch(void* const* d_in, const int* in_sizes, int n_in,
                              void* d_out, int out_size, void* d_ws, size_t ws_size,
                              hipStream_t stream) {
    const float* x       = (const float*)d_in[0];
    const float* w_norm  = (const float*)d_in[1];
    const float* W_in    = (const float*)d_in[2];
    const float* conv_w  = (const float*)d_in[3];
    const float* conv_b  = (const float*)d_in[4];
    const float* W_xproj = (const float*)d_in[5];
    const float* W_dt    = (const float*)d_in[6];
    const float* b_dt    = (const float*)d_in[7];
    const float* A_log   = (const float*)d_in[8];
    const float* Dp      = (const float*)d_in[9];
    const float* W_outp  = (const float*)d_in[10];
    const float* W_fc    = (const float*)d_in[11];
    const float* b_fc    = (const float*)d_in[12];
    const float* W_mu    = (const float*)d_in[13];
    const float* b_mu    = (const float*)d_in[14];
    const float* W_sig   = (const float*)d_in[15];
    const float* b_sig   = (const float*)d_in[16];
    float* out = (float*)d_out;

    char* p = (char*)d_ws;
    auto carve = [&](size_t bytes) { char* r = p; p += (bytes + 255) & ~(size_t)255; return r; };

    // shared small buffers (both modes)
    u16*   Wt   = (u16*)carve((size_t)N1 * K1 * 2);       // 8 MiB
    u16*   WxT  = (u16*)carve((size_t)128 * EDP * 2);
    u16*   WdtT = (u16*)carve((size_t)EDP * 64 * 2);
    float* syb  = (float*)carve((size_t)NB * EDP * 4);
    float* xmb  = (float*)carve((size_t)NB * DMP * 4);
    float* eb   = (float*)carve((size_t)NB * DMP * 4);

    // common prologue
    meanx_kernel <<<dim3(4, NB), 256, 0, stream>>>(x, xmb);
    packWt_kernel<<<dim3(128, 32), dim3(32, 8), 0, stream>>>(W_in, Wt);
    packWxT_kernel<<<1024, 256, 0, stream>>>(W_xproj, WxT);
    packWdtT_kernel<<<512, 256, 0, stream>>>(W_dt, WdtT);

    const bool batched = ws_size >= (size_t)260 * 1024 * 1024;

    if (batched) {
        // ---- batched layout (~237 MiB high-water) ----
        char*  reg0 = carve((size_t)MTOT * DMP * 2);          // 32 MiB: xn, later summaries
        char*  reg1 = carve((size_t)MTOT * EDP * 2);          // 64 MiB: xcr, later dlt
        u16*   zsb  = (u16*)carve((size_t)MTOT * EDP * 2);    // 64 MiB
        u16*   xca  = (u16*)carve((size_t)MTOT * EDP * 2);    // 64 MiB
        u16*   dtb  = (u16*)carve((size_t)MTOT * 64 * 2);
        float* bcb  = (float*)carve((size_t)MTOT * 16 * 4);

        u16*   xn   = (u16*)reg0;
        float* Pb   = (float*)reg0;                                 // 8 MiB
        float* wbuf = (float*)(reg0 + (size_t)8 * 1024 * 1024);     // 8 MiB
        float* hlb  = (float*)(reg0 + (size_t)16 * 1024 * 1024);    // 8 MiB
        float* accb = (float*)(reg0 + (size_t)24 * 1024 * 1024);    // 1 MiB
        u16*   xcr  = (u16*)reg1;
        u16*   dlt  = (u16*)reg1;

        rms_kernel <<<MTOT, 256, 0, stream>>>(x, w_norm, xn);
        gemm_bt<0><<<dim3(N1 / 128, MTOT / 128), 256, 0, stream>>>(xn, Wt, K1, K1, K1 / 32,
                                                                   xcr, zsb, nullptr, nullptr);
        conv_kernel<<<dim3(EDP / 256, MTOT), 256, 0, stream>>>(xcr, conv_w, conv_b, xca);
        gemm_bt<1><<<dim3(1, MTOT / 128), 256, 0, stream>>>(xca, WxT, EDP, EDP, EDP / 32,
                                                            dtb, nullptr, bcb, nullptr);
        gemm_bt<2><<<dim3(EDP / 128, MTOT / 128), 256, 0, stream>>>(dtb, WdtT, 64, 64, 2,
                                                                    dlt, nullptr, nullptr, b_dt);
        scan1_kernel<<<dim3(EDP / 256, NB, CHK), 256, 0, stream>>>(dlt, xca, zsb, bcb,
                                                                   A_log, Dp, Pb, wbuf, hlb, accb);
        scan2_kernel<<<dim3(EDP / 256, NB), 256, 0, stream>>>(Pb, wbuf, hlb, accb, syb);
    } else {
        // ---- lean per-batch layout (~38 MiB total) ----
        const int M = LSEQ;                                    // 2048 rows per batch
        char*  reg0 = carve((size_t)M * DMP * 2);              // 4 MiB: xn_b, later summaries
        char*  reg1 = carve((size_t)M * EDP * 2);              // 8 MiB: xcr_b, later dlt_b
        u16*   zsb  = (u16*)carve((size_t)M * EDP * 2);        // 8 MiB
        u16*   xca  = (u16*)carve((size_t)M * EDP * 2);        // 8 MiB
        u16*   dtb  = (u16*)carve((size_t)M * 64 * 2);
        float* bcb  = (float*)carve((size_t)M * 16 * 4);

        u16*   xn   = (u16*)reg0;
        float* Pb   = (float*)reg0;                                 // 1 MiB (CHK*NST*EDP*4)
        float* wbuf = (float*)(reg0 + (size_t)1 * 1024 * 1024);     // 1 MiB
        float* hlb  = (float*)(reg0 + (size_t)2 * 1024 * 1024);     // 1 MiB
        float* accb = (float*)(reg0 + (size_t)3 * 1024 * 1024);     // 128 KiB
        u16*   xcr  = (u16*)reg1;
        u16*   dlt  = (u16*)reg1;

        for (int b = 0; b < NB; ++b) {
            const float* xb = x + (size_t)b * LSEQ * DM;
            rms_kernel <<<M, 256, 0, stream>>>(xb, w_norm, xn);
            gemm_bt<0><<<dim3(N1 / 128, M / 128), 256, 0, stream>>>(xn, Wt, K1, K1, K1 / 32,
                                                                    xcr, zsb, nullptr, nullptr);
            conv_kernel<<<dim3(EDP / 256, M), 256, 0, stream>>>(xcr, conv_w, conv_b, xca);
            gemm_bt<1><<<dim3(1, M / 128), 256, 0, stream>>>(xca, WxT, EDP, EDP, EDP / 32,
                                                             dtb, nullptr, bcb, nullptr);
            gemm_bt<2><<<dim3(EDP / 128, M / 128), 256, 0, stream>>>(dtb, WdtT, 64, 64, 2,
                                                                     dlt, nullptr, nullptr, b_dt);
            // grid.y = 1 -> kernel sees b = 0; buffers are per-batch
            scan1_kernel<<<dim3(EDP / 256, 1, CHK), 256, 0, stream>>>(dlt, xca, zsb, bcb,
                                                                      A_log, Dp, Pb, wbuf, hlb, accb);
            scan2_kernel<<<dim3(EDP / 256, 1), 256, 0, stream>>>(Pb, wbuf, hlb, accb,
                                                                 syb + (size_t)b * EDP);
        }
    }

    e_kernel   <<<dim3(4, NB), 256, 0, stream>>>(syb, W_outp, xmb, eb);
    fc_kernel  <<<dim3(4, NB), 256, 0, stream>>>(eb, W_fc, b_fc, out);
    head_kernel<<<NB, 64, 0, stream>>>(out, W_mu, b_mu, W_sig, b_sig, out);
}

// Round 10
// 939.964 us; speedup vs baseline: 2.3025x; 2.3025x over previous
//
#include <hip/hip_runtime.h>

#define DM    1000
#define DMP   1024
#define ED    2000
#define EDP   2048
#define NST   8
#define LSEQ  2048
#define NB    8
#define MTOT  16384     // NB*LSEQ
#define N1    4096      // gemm1 padded N (2*ED)
#define K1    1024      // gemm1 padded K
#define CHK   16        // scan chunks
#define CLEN  (LSEQ/CHK)
#define MXCH  32        // meanx L-chunks

typedef unsigned short u16;
typedef __attribute__((ext_vector_type(4))) float f32x4;
typedef __attribute__((ext_vector_type(8))) short bf16x8;

__device__ __forceinline__ u16 f2bf(float f) {
    union { float f; unsigned u; } v; v.f = f;
    unsigned r = v.u + 0x7FFFu + ((v.u >> 16) & 1u);
    return (u16)(r >> 16);
}
__device__ __forceinline__ float bf2f(u16 h) {
    union { unsigned u; float f; } v; v.u = ((unsigned)h) << 16; return v.f;
}
__device__ __forceinline__ float siluf(float x) { return x / (1.f + __expf(-x)); }

// ---------------- mean over L of x: partial (L split MXCH ways) ----------------
__global__ void meanx_part(const float* __restrict__ x, float* __restrict__ part) {
    const int d = blockIdx.x * 256 + threadIdx.x;   // 0..1023
    const int b = blockIdx.y;
    const int c = blockIdx.z;                       // 0..MXCH-1
    float s = 0.f;
    if (d < DM) {
        const int l0 = c * (LSEQ / MXCH);
        for (int l = l0; l < l0 + LSEQ / MXCH; ++l)
            s += x[((size_t)b * LSEQ + l) * DM + d];
    }
    part[(size_t)(b * MXCH + c) * DMP + d] = s;
}
__global__ void meanx_red(const float* __restrict__ part, float* __restrict__ xm) {
    const int d = blockIdx.x * 256 + threadIdx.x;
    const int b = blockIdx.y;
    float s = 0.f;
    #pragma unroll
    for (int c = 0; c < MXCH; ++c) s += part[(size_t)(b * MXCH + c) * DMP + d];
    xm[b * DMP + d] = s * (1.f / LSEQ);
}

// ---------------- RMSNorm -> bf16 padded (row = blockIdx.x) ----------------
__global__ void rms_kernel(const float* __restrict__ x, const float* __restrict__ w,
                           u16* __restrict__ xn) {
    const int row = blockIdx.x;
    const int tid = threadIdx.x;
    const float* xr = x + (size_t)row * DM;
    float ss = 0.f;
    for (int i = tid; i < DM; i += 256) { float v = xr[i]; ss = fmaf(v, v, ss); }
    #pragma unroll
    for (int o = 32; o > 0; o >>= 1) ss += __shfl_xor(ss, o);
    __shared__ float red[4];
    if ((tid & 63) == 0) red[tid >> 6] = ss;
    __syncthreads();
    float tot = red[0] + red[1] + red[2] + red[3];
    float sc = rsqrtf(tot * (1.f / DM) + 1e-5f);
    for (int i = tid; i < DMP; i += 256)
        xn[(size_t)row * DMP + i] = (i < DM) ? f2bf(xr[i] * sc * w[i]) : (u16)0;
}

// ---------------- weight packs (transpose to [N][K] bf16, zero-padded) --------
__global__ void packWt_kernel(const float* __restrict__ W, u16* __restrict__ Wt) {
    __shared__ float t[32][33];
    int nt = blockIdx.x * 32, kt = blockIdx.y * 32;
    int tx = threadIdx.x, ty = threadIdx.y;   // 32 x 8
    for (int j = 0; j < 32; j += 8) {
        int k = kt + ty + j, n = nt + tx;
        t[ty + j][tx] = (k < DM && n < 2 * ED) ? W[(size_t)k * (2 * ED) + n] : 0.f;
    }
    __syncthreads();
    for (int j = 0; j < 32; j += 8) {
        int n = nt + ty + j, k = kt + tx;
        Wt[(size_t)n * K1 + k] = f2bf(t[tx][ty + j]);
    }
}
// W_xproj [2000][79] -> WxT [128][2048]
__global__ void packWxT_kernel(const float* __restrict__ W, u16* __restrict__ WxT) {
    int gid = blockIdx.x * 256 + threadIdx.x;       // 128*2048
    int n = gid >> 11, k = gid & (EDP - 1);
    int c = (n < 63) ? n : ((n >= 64 && n < 80) ? n - 1 : -1);
    float v = (c >= 0 && k < ED) ? W[(size_t)k * 79 + c] : 0.f;
    WxT[gid] = f2bf(v);
}
// W_dt [63][2000] -> WdtT [2048][64]
__global__ void packWdtT_kernel(const float* __restrict__ W, u16* __restrict__ Wt) {
    int gid = blockIdx.x * 256 + threadIdx.x;       // 2048*64
    int n = gid >> 6, k = gid & 63;
    float v = (n < ED && k < 63) ? W[(size_t)k * ED + n] : 0.f;
    Wt[gid] = f2bf(v);
}

// ---------------- MFMA GEMM: C[M,N] = A[M,K] * Bt[N,K]^T, 128x128 tile ------
template<int MODE>
__global__ __launch_bounds__(256, 2)
void gemm_bt(const u16* __restrict__ A, const u16* __restrict__ Bt,
             int lda, int ldb, int ksteps,
             u16* __restrict__ o0, u16* __restrict__ o1,
             float* __restrict__ of, const float* __restrict__ bias) {
    __shared__ u16 As[128 * 32];
    __shared__ u16 Bs[128 * 32];
    const int tid = threadIdx.x;
    const int wv = tid >> 6, ln = tid & 63;
    const int mbase = blockIdx.y << 7, nbase = blockIdx.x << 7;
    const int wm = (wv >> 1) << 6, wn = (wv & 1) << 6;
    const int fr = ln & 15, fo = ln >> 4;

    f32x4 acc[4][4];
    #pragma unroll
    for (int i = 0; i < 4; ++i)
        #pragma unroll
        for (int j = 0; j < 4; ++j) acc[i][j] = (f32x4){0.f, 0.f, 0.f, 0.f};

    for (int ks = 0; ks < ksteps; ++ks) {
        const int kt = ks << 5;
        __syncthreads();
        #pragma unroll
        for (int i = 0; i < 2; ++i) {
            int c = (wv << 7) + (i << 6) + ln;            // chunk id 0..511
            const u16* ga = A + (size_t)(mbase + (c >> 2)) * lda + kt + ((c & 3) << 3);
            __builtin_amdgcn_global_load_lds(
                (const __attribute__((address_space(1))) void*)ga,
                (__attribute__((address_space(3))) void*)&As[((wv << 7) + (i << 6)) * 8],
                16, 0, 0);
            const u16* gb = Bt + (size_t)(nbase + (c >> 2)) * ldb + kt + ((c & 3) << 3);
            __builtin_amdgcn_global_load_lds(
                (const __attribute__((address_space(1))) void*)gb,
                (__attribute__((address_space(3))) void*)&Bs[((wv << 7) + (i << 6)) * 8],
                16, 0, 0);
        }
        asm volatile("s_waitcnt vmcnt(0)" ::: "memory");
        __syncthreads();

        bf16x8 af[4], bg[4];
        #pragma unroll
        for (int i = 0; i < 4; ++i) {
            af[i] = *(const bf16x8*)&As[((wm + (i << 4) + fr) << 5) + (fo << 3)];
            bg[i] = *(const bf16x8*)&Bs[((wn + (i << 4) + fr) << 5) + (fo << 3)];
        }
        #pragma unroll
        for (int i = 0; i < 4; ++i)
            #pragma unroll
            for (int j = 0; j < 4; ++j)
                acc[i][j] = __builtin_amdgcn_mfma_f32_16x16x32_bf16(af[i], bg[j], acc[i][j], 0, 0, 0);
    }

    #pragma unroll
    for (int i = 0; i < 4; ++i) {
        #pragma unroll
        for (int j = 0; j < 4; ++j) {
            int col = nbase + wn + (j << 4) + fr;
            #pragma unroll
            for (int r = 0; r < 4; ++r) {
                int row = mbase + wm + (i << 4) + (fo << 2) + r;
                float v = acc[i][j][r];
                if (MODE == 0) {
                    if (col < ED)            o0[(size_t)row * EDP + col] = f2bf(v);
                    else if (col < 2 * ED)   o1[(size_t)row * EDP + (col - ED)] = f2bf(siluf(v));
                } else if (MODE == 1) {
                    if (col < 64)            o0[(size_t)row * 64 + col] = f2bf(v);
                    else if (col < 80)       of[(size_t)row * 16 + (col - 64)] = v;
                } else {
                    if (col < ED) {
                        float s = v + bias[col];
                        float sp = (s > 20.f) ? s : log1pf(__expf(s));
                        o0[(size_t)row * EDP + col] = f2bf(sp);
                    }
                }
            }
        }
    }
}

// ---------------- depthwise causal conv (K=4) + bias + silu ----------------
__global__ void conv_kernel(const u16* __restrict__ xcr, const float* __restrict__ cw,
                            const float* __restrict__ cb, u16* __restrict__ xca) {
    const int ed = blockIdx.x * 256 + threadIdx.x;
    const int row = blockIdx.y;
    if (ed >= ED) { xca[(size_t)row * EDP + ed] = 0; return; }
    const int l = row & (LSEQ - 1);
    const float4 w = ((const float4*)cw)[ed];
    float s = cb[ed];
    const float wj[4] = {w.x, w.y, w.z, w.w};
    #pragma unroll
    for (int j = 0; j < 4; ++j) {
        int lj = l - 3 + j;
        if (lj >= 0) s = fmaf(wj[j], bf2f(xcr[(size_t)(row - 3 + j) * EDP + ed]), s);
    }
    xca[(size_t)row * EDP + ed] = f2bf(siluf(s));
}

// ---------------- selective scan pass 1: per-chunk local scan --------------
__global__ void scan1_kernel(const u16* __restrict__ dlt, const u16* __restrict__ xca,
                             const u16* __restrict__ zs, const float* __restrict__ bc,
                             const float* __restrict__ A_log, const float* __restrict__ Dp,
                             float* __restrict__ Pb, float* __restrict__ wb,
                             float* __restrict__ hlb, float* __restrict__ accb) {
    const int ed = blockIdx.x * 256 + threadIdx.x;
    const int b = blockIdx.y;
    const int c = blockIdx.z;
    const int edc = (ed < ED) ? ed : (ED - 1);
    float An[NST];
    #pragma unroll
    for (int n = 0; n < NST; ++n) An[n] = -__expf(A_log[edc * NST + n]);
    const float dpv = Dp[edc];
    float g[NST], cd[NST], w[NST];
    #pragma unroll
    for (int n = 0; n < NST; ++n) { g[n] = 0.f; cd[n] = 1.f; w[n] = 0.f; }
    float acc = 0.f;

    const size_t rbase = (size_t)b * LSEQ + (size_t)c * CLEN;
    const float4* bc4 = (const float4*)bc;
    size_t i0 = rbase * EDP + ed;
    float dv = bf2f(dlt[i0]), xv = bf2f(xca[i0]), zv = bf2f(zs[i0]);
    float4 q0 = bc4[rbase * 4 + 0], q1 = bc4[rbase * 4 + 1];
    float4 q2 = bc4[rbase * 4 + 2], q3 = bc4[rbase * 4 + 3];

    for (int l = 0; l < CLEN; ++l) {
        float dv2 = 0.f, xv2 = 0.f, zv2 = 0.f;
        float4 p0 = make_float4(0.f,0.f,0.f,0.f), p1 = p0, p2 = p0, p3 = p0;
        if (l + 1 < CLEN) {
            size_t i2 = (rbase + l + 1) * EDP + ed;
            dv2 = bf2f(dlt[i2]); xv2 = bf2f(xca[i2]); zv2 = bf2f(zs[i2]);
            p0 = bc4[(rbase + l + 1) * 4 + 0]; p1 = bc4[(rbase + l + 1) * 4 + 1];
            p2 = bc4[(rbase + l + 1) * 4 + 2]; p3 = bc4[(rbase + l + 1) * 4 + 3];
        }
        const float Bv[8] = {q0.x,q0.y,q0.z,q0.w,q1.x,q1.y,q1.z,q1.w};
        const float Cv[8] = {q2.x,q2.y,q2.z,q2.w,q3.x,q3.y,q3.z,q3.w};
        float dx = dv * xv;
        float yl = 0.f;
        #pragma unroll
        for (int n = 0; n < NST; ++n) {
            float dA = __expf(dv * An[n]);
            cd[n] *= dA;
            g[n] = fmaf(g[n], dA, dx * Bv[n]);
            yl = fmaf(g[n], Cv[n], yl);
            w[n] = fmaf(zv * Cv[n], cd[n], w[n]);
        }
        acc = fmaf(yl + dpv * xv, zv, acc);
        dv = dv2; xv = xv2; zv = zv2; q0 = p0; q1 = p1; q2 = p2; q3 = p3;
    }
    const size_t o = ((size_t)(b * CHK + c) * NST) * EDP + ed;
    #pragma unroll
    for (int n = 0; n < NST; ++n) {
        Pb [o + (size_t)n * EDP] = cd[n];
        wb [o + (size_t)n * EDP] = w[n];
        hlb[o + (size_t)n * EDP] = g[n];
    }
    accb[(size_t)(b * CHK + c) * EDP + ed] = acc;
}

// ---------------- selective scan pass 2: serial recombine over chunks ------
__global__ void scan2_kernel(const float* __restrict__ Pb, const float* __restrict__ wb,
                             const float* __restrict__ hlb, const float* __restrict__ accb,
                             float* __restrict__ sy) {
    const int ed = blockIdx.x * 256 + threadIdx.x;
    const int b = blockIdx.y;
    float h[NST];
    #pragma unroll
    for (int n = 0; n < NST; ++n) h[n] = 0.f;
    float acc = 0.f;
    #pragma unroll
    for (int c = 0; c < CHK; ++c) {
        const size_t o = ((size_t)(b * CHK + c) * NST) * EDP + ed;
        acc += accb[(size_t)(b * CHK + c) * EDP + ed];
        #pragma unroll
        for (int n = 0; n < NST; ++n) acc = fmaf(wb[o + (size_t)n * EDP], h[n], acc);
        #pragma unroll
        for (int n = 0; n < NST; ++n)
            h[n] = fmaf(Pb[o + (size_t)n * EDP], h[n], hlb[o + (size_t)n * EDP]);
    }
    if (ed < ED) sy[b * EDP + ed] = acc * (1.f / LSEQ);
}

// ---------------- e = xmean + sy @ W_outp ----------------
__global__ void e_kernel(const float* __restrict__ sy, const float* __restrict__ Wo,
                         const float* __restrict__ xm, float* __restrict__ e) {
    const int d = blockIdx.x * 256 + threadIdx.x;
    const int b = blockIdx.y;
    if (d >= DM) return;
    float s = 0.f;
    for (int k = 0; k < ED; ++k) s = fmaf(sy[b * EDP + k], Wo[(size_t)k * DM + d], s);
    e[b * DMP + d] = s + xm[b * DMP + d];
}

// ---------------- h = elu(tanh(e @ W_fc + b_fc)) ----------------
__global__ void fc_kernel(const float* __restrict__ e, const float* __restrict__ Wfc,
                          const float* __restrict__ bfc, float* __restrict__ out) {
    const int d = blockIdx.x * 256 + threadIdx.x;
    const int b = blockIdx.y;
    if (d >= DM) return;
    float s = bfc[d];
    for (int k = 0; k < DM; ++k) s = fmaf(e[b * DMP + k], Wfc[(size_t)k * DM + d], s);
    float t = tanhf(s);
    out[b * DM + d] = (t > 0.f) ? t : expm1f(t);
}

// ---------------- mu / sigma heads ----------------
__global__ void head_kernel(const float* __restrict__ hout, const float* __restrict__ Wmu,
                            const float* __restrict__ bmu, const float* __restrict__ Wsig,
                            const float* __restrict__ bsig, float* __restrict__ out) {
    const int o = threadIdx.x;   // 64
    const int b = blockIdx.x;
    float sm = bmu[o], sg = bsig[o];
    for (int k = 0; k < DM; ++k) {
        float hv = hout[b * DM + k];
        sm = fmaf(hv, Wmu[k * 64 + o], sm);
        sg = fmaf(hv, Wsig[k * 64 + o], sg);
    }
    out[8000 + b * 64 + o] = sm;
    float el = (sg > 0.f) ? sg : expm1f(sg);
    out[8512 + b * 64 + o] = el + 1.f + 1e-14f;
}

extern "C" void kernel_launch(void* const* d_in, const int* in_sizes, int n_in,
                              void* d_out, int out_size, void* d_ws, size_t ws_size,
                              hipStream_t stream) {
    const float* x       = (const float*)d_in[0];
    const float* w_norm  = (const float*)d_in[1];
    const float* W_in    = (const float*)d_in[2];
    const float* conv_w  = (const float*)d_in[3];
    const float* conv_b  = (const float*)d_in[4];
    const float* W_xproj = (const float*)d_in[5];
    const float* W_dt    = (const float*)d_in[6];
    const float* b_dt    = (const float*)d_in[7];
    const float* A_log   = (const float*)d_in[8];
    const float* Dp      = (const float*)d_in[9];
    const float* W_outp  = (const float*)d_in[10];
    const float* W_fc    = (const float*)d_in[11];
    const float* b_fc    = (const float*)d_in[12];
    const float* W_mu    = (const float*)d_in[13];
    const float* b_mu    = (const float*)d_in[14];
    const float* W_sig   = (const float*)d_in[15];
    const float* b_sig   = (const float*)d_in[16];
    float* out = (float*)d_out;

    char* p = (char*)d_ws;
    auto al = [](size_t b) { return (b + 255) & ~(size_t)255; };
    auto carve = [&](size_t bytes) { char* r = p; p += al(bytes); return r; };

    // small buffers (always)
    u16*   Wt    = (u16*)carve((size_t)N1 * K1 * 2);       // 8 MiB
    u16*   WxT   = (u16*)carve((size_t)128 * EDP * 2);
    u16*   WdtT  = (u16*)carve((size_t)EDP * 64 * 2);
    float* syb   = (float*)carve((size_t)NB * EDP * 4);
    float* xmb   = (float*)carve((size_t)NB * DMP * 4);
    float* eb    = (float*)carve((size_t)NB * DMP * 4);
    float* mpart = (float*)carve((size_t)NB * MXCH * DMP * 4);   // 1 MiB

    // group-size selection: largest g in {8,4,2,1} whose big buffers fit ws
    size_t used = (size_t)(p - (char*)d_ws);
    size_t unit = al((size_t)LSEQ * DMP * 2) + 3 * al((size_t)LSEQ * EDP * 2)
                + al((size_t)LSEQ * 64 * 2) + al((size_t)LSEQ * 16 * 4);   // ~28.4 MiB/batch
    size_t avail = (ws_size > used) ? ws_size - used : 0;
    int g = 8;
    while (g > 1 && (size_t)g * unit > avail) g >>= 1;
    const int M = g * LSEQ;

    // big buffers, sized for one group of g batches (lifetime-aliased)
    char*  reg0 = carve((size_t)M * DMP * 2);          // g*4 MiB: xn, later summaries
    char*  reg1 = carve((size_t)M * EDP * 2);          // g*8 MiB: xcr, later dlt
    u16*   zsb  = (u16*)carve((size_t)M * EDP * 2);    // g*8 MiB
    u16*   xca  = (u16*)carve((size_t)M * EDP * 2);    // g*8 MiB
    u16*   dtb  = (u16*)carve((size_t)M * 64 * 2);
    float* bcb  = (float*)carve((size_t)M * 16 * 4);

    u16*   xn   = (u16*)reg0;
    const size_t MB1 = (size_t)1 << 20;                 // per-batch summary = 1 MiB each
    float* Pb   = (float*)reg0;
    float* wbuf = (float*)(reg0 + (size_t)g * MB1);
    float* hlb  = (float*)(reg0 + (size_t)2 * g * MB1);
    float* accb = (float*)(reg0 + (size_t)3 * g * MB1); // 3.125g MiB <= 4g MiB region
    u16*   xcr  = (u16*)reg1;
    u16*   dlt  = (u16*)reg1;

    // prologue (batch-independent)
    meanx_part <<<dim3(4, NB, MXCH), 256, 0, stream>>>(x, mpart);
    meanx_red  <<<dim3(4, NB), 256, 0, stream>>>(mpart, xmb);
    packWt_kernel<<<dim3(128, 32), dim3(32, 8), 0, stream>>>(W_in, Wt);
    packWxT_kernel<<<1024, 256, 0, stream>>>(W_xproj, WxT);
    packWdtT_kernel<<<512, 256, 0, stream>>>(W_dt, WdtT);

    for (int b0 = 0; b0 < NB; b0 += g) {
        const float* xg = x + (size_t)b0 * LSEQ * DM;
        rms_kernel <<<M, 256, 0, stream>>>(xg, w_norm, xn);
        gemm_bt<0><<<dim3(N1 / 128, M / 128), 256, 0, stream>>>(xn, Wt, K1, K1, K1 / 32,
                                                                xcr, zsb, nullptr, nullptr);
        conv_kernel<<<dim3(EDP / 256, M), 256, 0, stream>>>(xcr, conv_w, conv_b, xca);
        gemm_bt<1><<<dim3(1, M / 128), 256, 0, stream>>>(xca, WxT, EDP, EDP, EDP / 32,
                                                         dtb, nullptr, bcb, nullptr);
        gemm_bt<2><<<dim3(EDP / 128, M / 128), 256, 0, stream>>>(dtb, WdtT, 64, 64, 2,
                                                                 dlt, nullptr, nullptr, b_dt);
        scan1_kernel<<<dim3(EDP / 256, g, CHK), 256, 0, stream>>>(dlt, xca, zsb, bcb,
                                                                  A_log, Dp, Pb, wbuf, hlb, accb);
        scan2_kernel<<<dim3(EDP / 256, g), 256, 0, stream>>>(Pb, wbuf, hlb, accb,
                                                             syb + (size_t)b0 * EDP);
    }

    e_kernel   <<<dim3(4, NB), 256, 0, stream>>>(syb, W_outp, xmb, eb);
    fc_kernel  <<<dim3(4, NB), 256, 0, stream>>>(eb, W_fc, b_fc, out);
    head_kernel<<<NB, 64, 0, stream>>>(out, W_mu, b_mu, W_sig, b_sig, out);
}

// Round 11
// 931.813 us; speedup vs baseline: 2.3227x; 1.0087x over previous
//
#include <hip/hip_runtime.h>

#define DM    1000
#define DMP   1024
#define ED    2000
#define EDP   2048
#define NST   8
#define LSEQ  2048
#define NB    8
#define MTOT  16384     // NB*LSEQ
#define N1    4096      // gemm1 padded N (2*ED)
#define K1    1024      // gemm1 padded K
#define CHK   16        // scan chunks
#define CLEN  (LSEQ/CHK)
#define MXCH  32        // meanx L-chunks

typedef unsigned short u16;
typedef __attribute__((ext_vector_type(4))) float f32x4;
typedef __attribute__((ext_vector_type(8))) short bf16x8;

__device__ __forceinline__ u16 f2bf(float f) {
    union { float f; unsigned u; } v; v.f = f;
    unsigned r = v.u + 0x7FFFu + ((v.u >> 16) & 1u);
    return (u16)(r >> 16);
}
__device__ __forceinline__ float bf2f(u16 h) {
    union { unsigned u; float f; } v; v.u = ((unsigned)h) << 16; return v.f;
}
__device__ __forceinline__ float siluf(float x) { return x / (1.f + __expf(-x)); }

// ---------------- mean over L of x: partial (L split MXCH ways) ----------------
__global__ void meanx_part(const float* __restrict__ x, float* __restrict__ part) {
    const int d = blockIdx.x * 256 + threadIdx.x;   // 0..1023
    const int b = blockIdx.y;
    const int c = blockIdx.z;                       // 0..MXCH-1
    float s = 0.f;
    if (d < DM) {
        const int l0 = c * (LSEQ / MXCH);
        for (int l = l0; l < l0 + LSEQ / MXCH; ++l)
            s += x[((size_t)b * LSEQ + l) * DM + d];
    }
    part[(size_t)(b * MXCH + c) * DMP + d] = s;
}
__global__ void meanx_red(const float* __restrict__ part, float* __restrict__ xm) {
    const int d = blockIdx.x * 256 + threadIdx.x;
    const int b = blockIdx.y;
    float s = 0.f;
    #pragma unroll
    for (int c = 0; c < MXCH; ++c) s += part[(size_t)(b * MXCH + c) * DMP + d];
    xm[b * DMP + d] = s * (1.f / LSEQ);
}

// ---------------- RMSNorm -> bf16 padded (row = blockIdx.x) ----------------
__global__ void rms_kernel(const float* __restrict__ x, const float* __restrict__ w,
                           u16* __restrict__ xn) {
    const int row = blockIdx.x;
    const int tid = threadIdx.x;
    const float* xr = x + (size_t)row * DM;
    float ss = 0.f;
    for (int i = tid; i < DM; i += 256) { float v = xr[i]; ss = fmaf(v, v, ss); }
    #pragma unroll
    for (int o = 32; o > 0; o >>= 1) ss += __shfl_xor(ss, o);
    __shared__ float red[4];
    if ((tid & 63) == 0) red[tid >> 6] = ss;
    __syncthreads();
    float tot = red[0] + red[1] + red[2] + red[3];
    float sc = rsqrtf(tot * (1.f / DM) + 1e-5f);
    for (int i = tid; i < DMP; i += 256)
        xn[(size_t)row * DMP + i] = (i < DM) ? f2bf(xr[i] * sc * w[i]) : (u16)0;
}

// ---------------- weight packs (transpose to [N][K] bf16, zero-padded) --------
__global__ void packWt_kernel(const float* __restrict__ W, u16* __restrict__ Wt) {
    __shared__ float t[32][33];
    int nt = blockIdx.x * 32, kt = blockIdx.y * 32;
    int tx = threadIdx.x, ty = threadIdx.y;   // 32 x 8
    for (int j = 0; j < 32; j += 8) {
        int k = kt + ty + j, n = nt + tx;
        t[ty + j][tx] = (k < DM && n < 2 * ED) ? W[(size_t)k * (2 * ED) + n] : 0.f;
    }
    __syncthreads();
    for (int j = 0; j < 32; j += 8) {
        int n = nt + ty + j, k = kt + tx;
        Wt[(size_t)n * K1 + k] = f2bf(t[tx][ty + j]);
    }
}
// W_xproj [2000][79] -> WxT [128][2048]
__global__ void packWxT_kernel(const float* __restrict__ W, u16* __restrict__ WxT) {
    int gid = blockIdx.x * 256 + threadIdx.x;       // 128*2048
    int n = gid >> 11, k = gid & (EDP - 1);
    int c = (n < 63) ? n : ((n >= 64 && n < 80) ? n - 1 : -1);
    float v = (c >= 0 && k < ED) ? W[(size_t)k * 79 + c] : 0.f;
    WxT[gid] = f2bf(v);
}
// W_dt [63][2000] -> WdtT [2048][64]
__global__ void packWdtT_kernel(const float* __restrict__ W, u16* __restrict__ Wt) {
    int gid = blockIdx.x * 256 + threadIdx.x;       // 2048*64
    int n = gid >> 6, k = gid & 63;
    float v = (n < ED && k < 63) ? W[(size_t)k * ED + n] : 0.f;
    Wt[gid] = f2bf(v);
}

// ---------------- MFMA GEMM: C[M,N] = A[M,K] * Bt[N,K]^T, 128x128 tile ------
template<int MODE>
__global__ __launch_bounds__(256, 2)
void gemm_bt(const u16* __restrict__ A, const u16* __restrict__ Bt,
             int lda, int ldb, int ksteps,
             u16* __restrict__ o0, u16* __restrict__ o1,
             float* __restrict__ of, const float* __restrict__ bias) {
    __shared__ u16 As[128 * 32];
    __shared__ u16 Bs[128 * 32];
    const int tid = threadIdx.x;
    const int wv = tid >> 6, ln = tid & 63;
    const int mbase = blockIdx.y << 7, nbase = blockIdx.x << 7;
    const int wm = (wv >> 1) << 6, wn = (wv & 1) << 6;
    const int fr = ln & 15, fo = ln >> 4;

    f32x4 acc[4][4];
    #pragma unroll
    for (int i = 0; i < 4; ++i)
        #pragma unroll
        for (int j = 0; j < 4; ++j) acc[i][j] = (f32x4){0.f, 0.f, 0.f, 0.f};

    for (int ks = 0; ks < ksteps; ++ks) {
        const int kt = ks << 5;
        __syncthreads();
        #pragma unroll
        for (int i = 0; i < 2; ++i) {
            int c = (wv << 7) + (i << 6) + ln;            // chunk id 0..511
            const u16* ga = A + (size_t)(mbase + (c >> 2)) * lda + kt + ((c & 3) << 3);
            __builtin_amdgcn_global_load_lds(
                (const __attribute__((address_space(1))) void*)ga,
                (__attribute__((address_space(3))) void*)&As[((wv << 7) + (i << 6)) * 8],
                16, 0, 0);
            const u16* gb = Bt + (size_t)(nbase + (c >> 2)) * ldb + kt + ((c & 3) << 3);
            __builtin_amdgcn_global_load_lds(
                (const __attribute__((address_space(1))) void*)gb,
                (__attribute__((address_space(3))) void*)&Bs[((wv << 7) + (i << 6)) * 8],
                16, 0, 0);
        }
        asm volatile("s_waitcnt vmcnt(0)" ::: "memory");
        __syncthreads();

        bf16x8 af[4], bg[4];
        #pragma unroll
        for (int i = 0; i < 4; ++i) {
            af[i] = *(const bf16x8*)&As[((wm + (i << 4) + fr) << 5) + (fo << 3)];
            bg[i] = *(const bf16x8*)&Bs[((wn + (i << 4) + fr) << 5) + (fo << 3)];
        }
        #pragma unroll
        for (int i = 0; i < 4; ++i)
            #pragma unroll
            for (int j = 0; j < 4; ++j)
                acc[i][j] = __builtin_amdgcn_mfma_f32_16x16x32_bf16(af[i], bg[j], acc[i][j], 0, 0, 0);
    }

    #pragma unroll
    for (int i = 0; i < 4; ++i) {
        #pragma unroll
        for (int j = 0; j < 4; ++j) {
            int col = nbase + wn + (j << 4) + fr;
            #pragma unroll
            for (int r = 0; r < 4; ++r) {
                int row = mbase + wm + (i << 4) + (fo << 2) + r;
                float v = acc[i][j][r];
                if (MODE == 0) {
                    if (col < ED)            o0[(size_t)row * EDP + col] = f2bf(v);
                    else if (col < 2 * ED)   o1[(size_t)row * EDP + (col - ED)] = f2bf(siluf(v));
                } else if (MODE == 1) {
                    if (col < 64)            o0[(size_t)row * 64 + col] = f2bf(v);
                    else if (col < 80)       of[(size_t)row * 16 + (col - 64)] = v;
                } else {
                    if (col < ED) {
                        float s = v + bias[col];
                        float sp = (s > 20.f) ? s : log1pf(__expf(s));
                        o0[(size_t)row * EDP + col] = f2bf(sp);
                    }
                }
            }
        }
    }
}

// ---------------- depthwise causal conv (K=4) + bias + silu ----------------
__global__ void conv_kernel(const u16* __restrict__ xcr, const float* __restrict__ cw,
                            const float* __restrict__ cb, u16* __restrict__ xca) {
    const int ed = blockIdx.x * 256 + threadIdx.x;
    const int row = blockIdx.y;
    if (ed >= ED) { xca[(size_t)row * EDP + ed] = 0; return; }
    const int l = row & (LSEQ - 1);
    const float4 w = ((const float4*)cw)[ed];
    float s = cb[ed];
    const float wj[4] = {w.x, w.y, w.z, w.w};
    #pragma unroll
    for (int j = 0; j < 4; ++j) {
        int lj = l - 3 + j;
        if (lj >= 0) s = fmaf(wj[j], bf2f(xcr[(size_t)(row - 3 + j) * EDP + ed]), s);
    }
    xca[(size_t)row * EDP + ed] = f2bf(siluf(s));
}

// ---------------- selective scan pass 1: per-chunk local scan --------------
__global__ void scan1_kernel(const u16* __restrict__ dlt, const u16* __restrict__ xca,
                             const u16* __restrict__ zs, const float* __restrict__ bc,
                             const float* __restrict__ A_log, const float* __restrict__ Dp,
                             float* __restrict__ Pb, float* __restrict__ wb,
                             float* __restrict__ hlb, float* __restrict__ accb) {
    const int ed = blockIdx.x * 256 + threadIdx.x;
    const int b = blockIdx.y;
    const int c = blockIdx.z;
    const int edc = (ed < ED) ? ed : (ED - 1);
    float An[NST];
    #pragma unroll
    for (int n = 0; n < NST; ++n) An[n] = -__expf(A_log[edc * NST + n]);
    const float dpv = Dp[edc];
    float g[NST], cd[NST], w[NST];
    #pragma unroll
    for (int n = 0; n < NST; ++n) { g[n] = 0.f; cd[n] = 1.f; w[n] = 0.f; }
    float acc = 0.f;

    const size_t rbase = (size_t)b * LSEQ + (size_t)c * CLEN;
    const float4* bc4 = (const float4*)bc;
    size_t i0 = rbase * EDP + ed;
    float dv = bf2f(dlt[i0]), xv = bf2f(xca[i0]), zv = bf2f(zs[i0]);
    float4 q0 = bc4[rbase * 4 + 0], q1 = bc4[rbase * 4 + 1];
    float4 q2 = bc4[rbase * 4 + 2], q3 = bc4[rbase * 4 + 3];

    for (int l = 0; l < CLEN; ++l) {
        float dv2 = 0.f, xv2 = 0.f, zv2 = 0.f;
        float4 p0 = make_float4(0.f,0.f,0.f,0.f), p1 = p0, p2 = p0, p3 = p0;
        if (l + 1 < CLEN) {
            size_t i2 = (rbase + l + 1) * EDP + ed;
            dv2 = bf2f(dlt[i2]); xv2 = bf2f(xca[i2]); zv2 = bf2f(zs[i2]);
            p0 = bc4[(rbase + l + 1) * 4 + 0]; p1 = bc4[(rbase + l + 1) * 4 + 1];
            p2 = bc4[(rbase + l + 1) * 4 + 2]; p3 = bc4[(rbase + l + 1) * 4 + 3];
        }
        const float Bv[8] = {q0.x,q0.y,q0.z,q0.w,q1.x,q1.y,q1.z,q1.w};
        const float Cv[8] = {q2.x,q2.y,q2.z,q2.w,q3.x,q3.y,q3.z,q3.w};
        float dx = dv * xv;
        float yl = 0.f;
        #pragma unroll
        for (int n = 0; n < NST; ++n) {
            float dA = __expf(dv * An[n]);
            cd[n] *= dA;
            g[n] = fmaf(g[n], dA, dx * Bv[n]);
            yl = fmaf(g[n], Cv[n], yl);
            w[n] = fmaf(zv * Cv[n], cd[n], w[n]);
        }
        acc = fmaf(yl + dpv * xv, zv, acc);
        dv = dv2; xv = xv2; zv = zv2; q0 = p0; q1 = p1; q2 = p2; q3 = p3;
    }
    const size_t o = ((size_t)(b * CHK + c) * NST) * EDP + ed;
    #pragma unroll
    for (int n = 0; n < NST; ++n) {
        Pb [o + (size_t)n * EDP] = cd[n];
        wb [o + (size_t)n * EDP] = w[n];
        hlb[o + (size_t)n * EDP] = g[n];
    }
    accb[(size_t)(b * CHK + c) * EDP + ed] = acc;
}

// ---------------- selective scan pass 2: serial recombine over chunks ------
__global__ void scan2_kernel(const float* __restrict__ Pb, const float* __restrict__ wb,
                             const float* __restrict__ hlb, const float* __restrict__ accb,
                             float* __restrict__ sy) {
    const int ed = blockIdx.x * 256 + threadIdx.x;
    const int b = blockIdx.y;
    float h[NST];
    #pragma unroll
    for (int n = 0; n < NST; ++n) h[n] = 0.f;
    float acc = 0.f;
    #pragma unroll
    for (int c = 0; c < CHK; ++c) {
        const size_t o = ((size_t)(b * CHK + c) * NST) * EDP + ed;
        acc += accb[(size_t)(b * CHK + c) * EDP + ed];
        #pragma unroll
        for (int n = 0; n < NST; ++n) acc = fmaf(wb[o + (size_t)n * EDP], h[n], acc);
        #pragma unroll
        for (int n = 0; n < NST; ++n)
            h[n] = fmaf(Pb[o + (size_t)n * EDP], h[n], hlb[o + (size_t)n * EDP]);
    }
    if (ed < ED) sy[b * EDP + ed] = acc * (1.f / LSEQ);
}

// ---------------- e = xmean + sy @ W_outp  (split-K: 8 chunks of 250) ------
__global__ void e_part(const float* __restrict__ sy, const float* __restrict__ Wo,
                       float* __restrict__ ep) {
    const int d = blockIdx.x * 256 + threadIdx.x;
    const int b = blockIdx.y;
    const int kc = blockIdx.z;                    // 0..7
    if (d >= DM) return;
    float s = 0.f;
    const int k0 = kc * 250;
    for (int k = k0; k < k0 + 250; ++k)
        s = fmaf(sy[b * EDP + k], Wo[(size_t)k * DM + d], s);
    ep[(size_t)(b * 8 + kc) * DMP + d] = s;
}
__global__ void e_red(const float* __restrict__ ep, const float* __restrict__ xm,
                      float* __restrict__ e) {
    const int d = blockIdx.x * 256 + threadIdx.x;
    const int b = blockIdx.y;
    if (d >= DM) return;
    float s = xm[b * DMP + d];
    #pragma unroll
    for (int kc = 0; kc < 8; ++kc) s += ep[(size_t)(b * 8 + kc) * DMP + d];
    e[b * DMP + d] = s;
}

// ---------------- h = elu(tanh(e @ W_fc + b_fc))  (split-K: 4 x 250) -------
__global__ void fc_part(const float* __restrict__ e, const float* __restrict__ Wfc,
                        float* __restrict__ fp) {
    const int d = blockIdx.x * 256 + threadIdx.x;
    const int b = blockIdx.y;
    const int kc = blockIdx.z;                    // 0..3
    if (d >= DM) return;
    float s = 0.f;
    const int k0 = kc * 250;
    for (int k = k0; k < k0 + 250; ++k)
        s = fmaf(e[b * DMP + k], Wfc[(size_t)k * DM + d], s);
    fp[(size_t)(b * 4 + kc) * DMP + d] = s;
}
__global__ void fc_red(const float* __restrict__ fp, const float* __restrict__ bfc,
                       float* __restrict__ out) {
    const int d = blockIdx.x * 256 + threadIdx.x;
    const int b = blockIdx.y;
    if (d >= DM) return;
    float s = bfc[d];
    #pragma unroll
    for (int kc = 0; kc < 4; ++kc) s += fp[(size_t)(b * 4 + kc) * DMP + d];
    float t = tanhf(s);
    out[b * DM + d] = (t > 0.f) ? t : expm1f(t);
}

// ---------------- mu / sigma heads  (split-K: 8 x 125) ---------------------
__global__ void head_part(const float* __restrict__ hout, const float* __restrict__ Wmu,
                          const float* __restrict__ Wsig, float* __restrict__ hp) {
    const int o = threadIdx.x;                    // 64
    const int b = blockIdx.x;
    const int kc = blockIdx.y;                    // 0..7
    float sm = 0.f, sg = 0.f;
    const int k0 = kc * 125;
    for (int k = k0; k < k0 + 125; ++k) {
        float hv = hout[b * DM + k];
        sm = fmaf(hv, Wmu[k * 64 + o], sm);
        sg = fmaf(hv, Wsig[k * 64 + o], sg);
    }
    hp[(size_t)(b * 8 + kc) * 128 + o]      = sm;
    hp[(size_t)(b * 8 + kc) * 128 + 64 + o] = sg;
}
__global__ void head_red(const float* __restrict__ hp, const float* __restrict__ bmu,
                         const float* __restrict__ bsig, float* __restrict__ out) {
    const int o = threadIdx.x;                    // 64
    const int b = blockIdx.x;
    float sm = bmu[o], sg = bsig[o];
    #pragma unroll
    for (int kc = 0; kc < 8; ++kc) {
        sm += hp[(size_t)(b * 8 + kc) * 128 + o];
        sg += hp[(size_t)(b * 8 + kc) * 128 + 64 + o];
    }
    out[8000 + b * 64 + o] = sm;
    float el = (sg > 0.f) ? sg : expm1f(sg);
    out[8512 + b * 64 + o] = el + 1.f + 1e-14f;
}

extern "C" void kernel_launch(void* const* d_in, const int* in_sizes, int n_in,
                              void* d_out, int out_size, void* d_ws, size_t ws_size,
                              hipStream_t stream) {
    const float* x       = (const float*)d_in[0];
    const float* w_norm  = (const float*)d_in[1];
    const float* W_in    = (const float*)d_in[2];
    const float* conv_w  = (const float*)d_in[3];
    const float* conv_b  = (const float*)d_in[4];
    const float* W_xproj = (const float*)d_in[5];
    const float* W_dt    = (const float*)d_in[6];
    const float* b_dt    = (const float*)d_in[7];
    const float* A_log   = (const float*)d_in[8];
    const float* Dp      = (const float*)d_in[9];
    const float* W_outp  = (const float*)d_in[10];
    const float* W_fc    = (const float*)d_in[11];
    const float* b_fc    = (const float*)d_in[12];
    const float* W_mu    = (const float*)d_in[13];
    const float* b_mu    = (const float*)d_in[14];
    const float* W_sig   = (const float*)d_in[15];
    const float* b_sig   = (const float*)d_in[16];
    float* out = (float*)d_out;

    char* p = (char*)d_ws;
    auto al = [](size_t b) { return (b + 255) & ~(size_t)255; };
    auto carve = [&](size_t bytes) { char* r = p; p += al(bytes); return r; };

    // small buffers (always)
    u16*   Wt    = (u16*)carve((size_t)N1 * K1 * 2);       // 8 MiB
    u16*   WxT   = (u16*)carve((size_t)128 * EDP * 2);
    u16*   WdtT  = (u16*)carve((size_t)EDP * 64 * 2);
    float* syb   = (float*)carve((size_t)NB * EDP * 4);
    float* xmb   = (float*)carve((size_t)NB * DMP * 4);
    float* eb    = (float*)carve((size_t)NB * DMP * 4);
    float* mpart = (float*)carve((size_t)NB * MXCH * DMP * 4);   // 1 MiB
    float* ep    = (float*)carve((size_t)NB * 8 * DMP * 4);      // 256 KiB
    float* fp    = (float*)carve((size_t)NB * 4 * DMP * 4);      // 128 KiB
    float* hp    = (float*)carve((size_t)NB * 8 * 128 * 4);      // 32 KiB

    // group-size selection: largest g in {8,4,2,1} whose big buffers fit ws
    size_t used = (size_t)(p - (char*)d_ws);
    size_t unit = al((size_t)LSEQ * DMP * 2) + 3 * al((size_t)LSEQ * EDP * 2)
                + al((size_t)LSEQ * 64 * 2) + al((size_t)LSEQ * 16 * 4);   // ~28.4 MiB/batch
    size_t avail = (ws_size > used) ? ws_size - used : 0;
    int g = 8;
    while (g > 1 && (size_t)g * unit > avail) g >>= 1;
    const int M = g * LSEQ;

    // big buffers, sized for one group of g batches (lifetime-aliased)
    char*  reg0 = carve((size_t)M * DMP * 2);          // g*4 MiB: xn, later summaries
    char*  reg1 = carve((size_t)M * EDP * 2);          // g*8 MiB: xcr, later dlt
    u16*   zsb  = (u16*)carve((size_t)M * EDP * 2);    // g*8 MiB
    u16*   xca  = (u16*)carve((size_t)M * EDP * 2);    // g*8 MiB
    u16*   dtb  = (u16*)carve((size_t)M * 64 * 2);
    float* bcb  = (float*)carve((size_t)M * 16 * 4);

    u16*   xn   = (u16*)reg0;
    const size_t MB1 = (size_t)1 << 20;                 // per-batch summary = 1 MiB each
    float* Pb   = (float*)reg0;
    float* wbuf = (float*)(reg0 + (size_t)g * MB1);
    float* hlb  = (float*)(reg0 + (size_t)2 * g * MB1);
    float* accb = (float*)(reg0 + (size_t)3 * g * MB1); // 3.125g MiB <= 4g MiB region
    u16*   xcr  = (u16*)reg1;
    u16*   dlt  = (u16*)reg1;

    // prologue (batch-independent)
    meanx_part <<<dim3(4, NB, MXCH), 256, 0, stream>>>(x, mpart);
    meanx_red  <<<dim3(4, NB), 256, 0, stream>>>(mpart, xmb);
    packWt_kernel<<<dim3(128, 32), dim3(32, 8), 0, stream>>>(W_in, Wt);
    packWxT_kernel<<<1024, 256, 0, stream>>>(W_xproj, WxT);
    packWdtT_kernel<<<512, 256, 0, stream>>>(W_dt, WdtT);

    for (int b0 = 0; b0 < NB; b0 += g) {
        const float* xg = x + (size_t)b0 * LSEQ * DM;
        rms_kernel <<<M, 256, 0, stream>>>(xg, w_norm, xn);
        gemm_bt<0><<<dim3(N1 / 128, M / 128), 256, 0, stream>>>(xn, Wt, K1, K1, K1 / 32,
                                                                xcr, zsb, nullptr, nullptr);
        conv_kernel<<<dim3(EDP / 256, M), 256, 0, stream>>>(xcr, conv_w, conv_b, xca);
        gemm_bt<1><<<dim3(1, M / 128), 256, 0, stream>>>(xca, WxT, EDP, EDP, EDP / 32,
                                                         dtb, nullptr, bcb, nullptr);
        gemm_bt<2><<<dim3(EDP / 128, M / 128), 256, 0, stream>>>(dtb, WdtT, 64, 64, 2,
                                                                 dlt, nullptr, nullptr, b_dt);
        scan1_kernel<<<dim3(EDP / 256, g, CHK), 256, 0, stream>>>(dlt, xca, zsb, bcb,
                                                                  A_log, Dp, Pb, wbuf, hlb, accb);
        scan2_kernel<<<dim3(EDP / 256, g), 256, 0, stream>>>(Pb, wbuf, hlb, accb,
                                                             syb + (size_t)b0 * EDP);
    }

    e_part <<<dim3(4, NB, 8), 256, 0, stream>>>(syb, W_outp, ep);
    e_red  <<<dim3(4, NB), 256, 0, stream>>>(ep, xmb, eb);
    fc_part<<<dim3(4, NB, 4), 256, 0, stream>>>(eb, W_fc, fp);
    fc_red <<<dim3(4, NB), 256, 0, stream>>>(fp, b_fc, out);
    head_part<<<dim3(NB, 8), 64, 0, stream>>>(out, W_mu, W_sig, hp);
    head_red <<<NB, 64, 0, stream>>>(hp, b_mu, b_sig, out);
}

// Round 13
// 921.072 us; speedup vs baseline: 2.3498x; 1.0117x over previous
//
#include <hip/hip_runtime.h>

#define DM    1000
#define DMP   1024
#define ED    2000
#define EDP   2048
#define NST   8
#define LSEQ  2048
#define NB    8
#define MTOT  16384     // NB*LSEQ
#define N1    4096      // gemm1 padded N (2*ED)
#define K1    1024      // gemm1 padded K
#define CHK   16        // scan chunks
#define CLEN  (LSEQ/CHK)
#define MXCH  32        // meanx L-chunks

typedef unsigned short u16;
typedef __attribute__((ext_vector_type(4))) float f32x4;
typedef __attribute__((ext_vector_type(8))) short bf16x8;
typedef __attribute__((ext_vector_type(4))) unsigned short u16x4;

__device__ __forceinline__ u16 f2bf(float f) {
    union { float f; unsigned u; } v; v.f = f;
    unsigned r = v.u + 0x7FFFu + ((v.u >> 16) & 1u);
    return (u16)(r >> 16);
}
__device__ __forceinline__ float bf2f(u16 h) {
    union { unsigned u; float f; } v; v.u = ((unsigned)h) << 16; return v.f;
}
__device__ __forceinline__ float siluf(float x) { return x / (1.f + __expf(-x)); }

// ---------------- mean over L of x: partial, float4 ----------------
__global__ void meanx_part(const float* __restrict__ x, float* __restrict__ part) {
    const int t = threadIdx.x;                      // 0..255 -> d4
    const int b = blockIdx.y;
    const int c = blockIdx.z;
    float4 s = make_float4(0.f, 0.f, 0.f, 0.f);
    if (t < 250) {
        const int l0 = c * (LSEQ / MXCH);
        for (int l = l0; l < l0 + LSEQ / MXCH; ++l) {
            float4 v = ((const float4*)(x + ((size_t)b * LSEQ + l) * DM))[t];
            s.x += v.x; s.y += v.y; s.z += v.z; s.w += v.w;
        }
    }
    ((float4*)(part + (size_t)(b * MXCH + c) * DMP))[t] = s;
}
__global__ void meanx_red(const float* __restrict__ part, float* __restrict__ xm) {
    const int d = blockIdx.x * 256 + threadIdx.x;
    const int b = blockIdx.y;
    float s = 0.f;
    #pragma unroll
    for (int c = 0; c < MXCH; ++c) s += part[(size_t)(b * MXCH + c) * DMP + d];
    xm[b * DMP + d] = s * (1.f / LSEQ);
}

// ---------------- RMSNorm -> bf16 padded, float4 in / ushort4 out ----------
__global__ void rms_kernel(const float* __restrict__ x, const float* __restrict__ w,
                           u16* __restrict__ xn) {
    const int row = blockIdx.x;
    const int tid = threadIdx.x;
    const float* xr = x + (size_t)row * DM;
    float ss = 0.f;
    if (tid < 250) {
        float4 v = ((const float4*)xr)[tid];
        ss = v.x * v.x + v.y * v.y + v.z * v.z + v.w * v.w;
    }
    #pragma unroll
    for (int o = 32; o > 0; o >>= 1) ss += __shfl_xor(ss, o);
    __shared__ float red[4];
    if ((tid & 63) == 0) red[tid >> 6] = ss;
    __syncthreads();
    float tot = red[0] + red[1] + red[2] + red[3];
    float sc = rsqrtf(tot * (1.f / DM) + 1e-5f);
    u16x4 o4 = (u16x4){0, 0, 0, 0};
    if (tid < 250) {
        float4 v = ((const float4*)xr)[tid];
        float4 g = ((const float4*)w)[tid];
        o4[0] = f2bf(v.x * sc * g.x); o4[1] = f2bf(v.y * sc * g.y);
        o4[2] = f2bf(v.z * sc * g.z); o4[3] = f2bf(v.w * sc * g.w);
    }
    *(u16x4*)&xn[(size_t)row * DMP + 4 * tid] = o4;
}

// ---------------- weight packs ----------------
__global__ void packWt_kernel(const float* __restrict__ W, u16* __restrict__ Wt) {
    __shared__ float t[32][33];
    int nt = blockIdx.x * 32, kt = blockIdx.y * 32;
    int tx = threadIdx.x, ty = threadIdx.y;   // 32 x 8
    for (int j = 0; j < 32; j += 8) {
        int k = kt + ty + j, n = nt + tx;
        t[ty + j][tx] = (k < DM && n < 2 * ED) ? W[(size_t)k * (2 * ED) + n] : 0.f;
    }
    __syncthreads();
    for (int j = 0; j < 32; j += 8) {
        int n = nt + ty + j, k = kt + tx;
        Wt[(size_t)n * K1 + k] = f2bf(t[tx][ty + j]);
    }
}
__global__ void packWxT_kernel(const float* __restrict__ W, u16* __restrict__ WxT) {
    int gid = blockIdx.x * 256 + threadIdx.x;       // 128*2048
    int n = gid >> 11, k = gid & (EDP - 1);
    int c = (n < 63) ? n : ((n >= 64 && n < 80) ? n - 1 : -1);
    float v = (c >= 0 && k < ED) ? W[(size_t)k * 79 + c] : 0.f;
    WxT[gid] = f2bf(v);
}
__global__ void packWdtT_kernel(const float* __restrict__ W, u16* __restrict__ Wt) {
    int gid = blockIdx.x * 256 + threadIdx.x;       // 2048*64
    int n = gid >> 6, k = gid & 63;
    float v = (n < ED && k < 63) ? W[(size_t)k * ED + n] : 0.f;
    Wt[gid] = f2bf(v);
}

// ---------------- MFMA GEMM with XCD-aware block swizzle --------------------
// requires gridDim.x*gridDim.y % 8 == 0 (all call sites satisfy)
template<int MODE>
__global__ __launch_bounds__(256, 2)
void gemm_bt(const u16* __restrict__ A, const u16* __restrict__ Bt,
             int lda, int ldb, int ksteps,
             u16* __restrict__ o0, u16* __restrict__ o1,
             float* __restrict__ of, const float* __restrict__ bias) {
    __shared__ u16 As[128 * 32];
    __shared__ u16 Bs[128 * 32];
    const int tid = threadIdx.x;
    const int wv = tid >> 6, ln = tid & 63;
    const int nwg = gridDim.x * gridDim.y;
    const int fid = blockIdx.y * gridDim.x + blockIdx.x;
    const int sw  = ((fid & 7) * (nwg >> 3)) + (fid >> 3);
    const int mbase = (sw / gridDim.x) << 7, nbase = (sw % gridDim.x) << 7;
    const int wm = (wv >> 1) << 6, wn = (wv & 1) << 6;
    const int fr = ln & 15, fo = ln >> 4;

    f32x4 acc[4][4];
    #pragma unroll
    for (int i = 0; i < 4; ++i)
        #pragma unroll
        for (int j = 0; j < 4; ++j) acc[i][j] = (f32x4){0.f, 0.f, 0.f, 0.f};

    for (int ks = 0; ks < ksteps; ++ks) {
        const int kt = ks << 5;
        __syncthreads();
        #pragma unroll
        for (int i = 0; i < 2; ++i) {
            int c = (wv << 7) + (i << 6) + ln;            // chunk id 0..511
            const u16* ga = A + (size_t)(mbase + (c >> 2)) * lda + kt + ((c & 3) << 3);
            __builtin_amdgcn_global_load_lds(
                (const __attribute__((address_space(1))) void*)ga,
                (__attribute__((address_space(3))) void*)&As[((wv << 7) + (i << 6)) * 8],
                16, 0, 0);
            const u16* gb = Bt + (size_t)(nbase + (c >> 2)) * ldb + kt + ((c & 3) << 3);
            __builtin_amdgcn_global_load_lds(
                (const __attribute__((address_space(1))) void*)gb,
                (__attribute__((address_space(3))) void*)&Bs[((wv << 7) + (i << 6)) * 8],
                16, 0, 0);
        }
        asm volatile("s_waitcnt vmcnt(0)" ::: "memory");
        __syncthreads();

        bf16x8 af[4], bg[4];
        #pragma unroll
        for (int i = 0; i < 4; ++i) {
            af[i] = *(const bf16x8*)&As[((wm + (i << 4) + fr) << 5) + (fo << 3)];
            bg[i] = *(const bf16x8*)&Bs[((wn + (i << 4) + fr) << 5) + (fo << 3)];
        }
        #pragma unroll
        for (int i = 0; i < 4; ++i)
            #pragma unroll
            for (int j = 0; j < 4; ++j)
                acc[i][j] = __builtin_amdgcn_mfma_f32_16x16x32_bf16(af[i], bg[j], acc[i][j], 0, 0, 0);
    }

    #pragma unroll
    for (int i = 0; i < 4; ++i) {
        #pragma unroll
        for (int j = 0; j < 4; ++j) {
            int col = nbase + wn + (j << 4) + fr;
            #pragma unroll
            for (int r = 0; r < 4; ++r) {
                int row = mbase + wm + (i << 4) + (fo << 2) + r;
                float v = acc[i][j][r];
                if (MODE == 0) {
                    if (col < ED)            o0[(size_t)row * EDP + col] = f2bf(v);
                    else if (col < 2 * ED)   o1[(size_t)row * EDP + (col - ED)] = f2bf(siluf(v));
                } else if (MODE == 1) {
                    if (col < 64)            o0[(size_t)row * 64 + col] = f2bf(v);
                    else if (col < 80)       of[(size_t)row * 16 + (col - 64)] = v;
                } else {
                    if (col < ED) {
                        float s = v + bias[col];
                        float sp = (s > 20.f) ? s : log1pf(__expf(s));
                        o0[(size_t)row * EDP + col] = f2bf(sp);
                    }
                }
            }
        }
    }
}

// ---------------- depthwise causal conv, 8 channels/thread (short8) --------
__global__ void conv_kernel(const u16* __restrict__ xcr, const float* __restrict__ cw,
                            const float* __restrict__ cb, u16* __restrict__ xca) {
    const int e8 = threadIdx.x;                   // 0..255
    const int row = blockIdx.x;
    const int ed0 = e8 * 8;
    const size_t base = (size_t)row * EDP + ed0;
    if (ed0 >= ED) {
        *(bf16x8*)&xca[base] = (bf16x8){0, 0, 0, 0, 0, 0, 0, 0};
        return;
    }
    const int l = row & (LSEQ - 1);
    float wv[8][4], acc[8];
    #pragma unroll
    for (int t = 0; t < 8; ++t) {
        float4 q = ((const float4*)cw)[ed0 + t];
        wv[t][0] = q.x; wv[t][1] = q.y; wv[t][2] = q.z; wv[t][3] = q.w;
    }
    {
        float4 b0 = ((const float4*)cb)[e8 * 2];
        float4 b1 = ((const float4*)cb)[e8 * 2 + 1];
        acc[0] = b0.x; acc[1] = b0.y; acc[2] = b0.z; acc[3] = b0.w;
        acc[4] = b1.x; acc[5] = b1.y; acc[6] = b1.z; acc[7] = b1.w;
    }
    #pragma unroll
    for (int j = 0; j < 4; ++j) {
        if (l - 3 + j >= 0) {
            bf16x8 r = *(const bf16x8*)&xcr[(size_t)(row - 3 + j) * EDP + ed0];
            #pragma unroll
            for (int t = 0; t < 8; ++t)
                acc[t] = fmaf(wv[t][j], bf2f((u16)r[t]), acc[t]);
        }
    }
    bf16x8 o;
    #pragma unroll
    for (int t = 0; t < 8; ++t) o[t] = (short)f2bf(siluf(acc[t]));
    *(bf16x8*)&xca[base] = o;
}

// ---------------- selective scan pass 1: per-chunk local scan --------------
__global__ void scan1_kernel(const u16* __restrict__ dlt, const u16* __restrict__ xca,
                             const u16* __restrict__ zs, const float* __restrict__ bc,
                             const float* __restrict__ A_log, const float* __restrict__ Dp,
                             float* __restrict__ Pb, float* __restrict__ wb,
                             float* __restrict__ hlb, float* __restrict__ accb) {
    const int ed = blockIdx.x * 256 + threadIdx.x;
    const int b = blockIdx.y;
    const int c = blockIdx.z;
    const int edc = (ed < ED) ? ed : (ED - 1);
    float An[NST];
    #pragma unroll
    for (int n = 0; n < NST; ++n) An[n] = -__expf(A_log[edc * NST + n]);
    const float dpv = Dp[edc];
    float g[NST], cd[NST], w[NST];
    #pragma unroll
    for (int n = 0; n < NST; ++n) { g[n] = 0.f; cd[n] = 1.f; w[n] = 0.f; }
    float acc = 0.f;

    const size_t rbase = (size_t)b * LSEQ + (size_t)c * CLEN;
    const float4* bc4 = (const float4*)bc;
    size_t i0 = rbase * EDP + ed;
    float dv = bf2f(dlt[i0]), xv = bf2f(xca[i0]), zv = bf2f(zs[i0]);
    float4 q0 = bc4[rbase * 4 + 0], q1 = bc4[rbase * 4 + 1];
    float4 q2 = bc4[rbase * 4 + 2], q3 = bc4[rbase * 4 + 3];

    for (int l = 0; l < CLEN; ++l) {
        float dv2 = 0.f, xv2 = 0.f, zv2 = 0.f;
        float4 p0 = make_float4(0.f,0.f,0.f,0.f), p1 = p0, p2 = p0, p3 = p0;
        if (l + 1 < CLEN) {
            size_t i2 = (rbase + l + 1) * EDP + ed;
            dv2 = bf2f(dlt[i2]); xv2 = bf2f(xca[i2]); zv2 = bf2f(zs[i2]);
            p0 = bc4[(rbase + l + 1) * 4 + 0]; p1 = bc4[(rbase + l + 1) * 4 + 1];
            p2 = bc4[(rbase + l + 1) * 4 + 2]; p3 = bc4[(rbase + l + 1) * 4 + 3];
        }
        const float Bv[8] = {q0.x,q0.y,q0.z,q0.w,q1.x,q1.y,q1.z,q1.w};
        const float Cv[8] = {q2.x,q2.y,q2.z,q2.w,q3.x,q3.y,q3.z,q3.w};
        float dx = dv * xv;
        float yl = 0.f;
        #pragma unroll
        for (int n = 0; n < NST; ++n) {
            float dA = __expf(dv * An[n]);
            cd[n] *= dA;
            g[n] = fmaf(g[n], dA, dx * Bv[n]);
            yl = fmaf(g[n], Cv[n], yl);
            w[n] = fmaf(zv * Cv[n], cd[n], w[n]);
        }
        acc = fmaf(yl + dpv * xv, zv, acc);
        dv = dv2; xv = xv2; zv = zv2; q0 = p0; q1 = p1; q2 = p2; q3 = p3;
    }
    const size_t o = ((size_t)(b * CHK + c) * NST) * EDP + ed;
    #pragma unroll
    for (int n = 0; n < NST; ++n) {
        Pb [o + (size_t)n * EDP] = cd[n];
        wb [o + (size_t)n * EDP] = w[n];
        hlb[o + (size_t)n * EDP] = g[n];
    }
    accb[(size_t)(b * CHK + c) * EDP + ed] = acc;
}

// ---------------- selective scan pass 2 ------------------------------------
__global__ void scan2_kernel(const float* __restrict__ Pb, const float* __restrict__ wb,
                             const float* __restrict__ hlb, const float* __restrict__ accb,
                             float* __restrict__ sy) {
    const int ed = blockIdx.x * 256 + threadIdx.x;
    const int b = blockIdx.y;
    float h[NST];
    #pragma unroll
    for (int n = 0; n < NST; ++n) h[n] = 0.f;
    float acc = 0.f;
    #pragma unroll
    for (int c = 0; c < CHK; ++c) {
        const size_t o = ((size_t)(b * CHK + c) * NST) * EDP + ed;
        acc += accb[(size_t)(b * CHK + c) * EDP + ed];
        #pragma unroll
        for (int n = 0; n < NST; ++n) acc = fmaf(wb[o + (size_t)n * EDP], h[n], acc);
        #pragma unroll
        for (int n = 0; n < NST; ++n)
            h[n] = fmaf(Pb[o + (size_t)n * EDP], h[n], hlb[o + (size_t)n * EDP]);
    }
    if (ed < ED) sy[b * EDP + ed] = acc * (1.f / LSEQ);
}

// ---- e: all batches per block, weights streamed once (16 chunks of 125) ----
__global__ void e_part(const float* __restrict__ sy, const float* __restrict__ Wo,
                       float* __restrict__ ep) {
    const int d = blockIdx.x * 256 + threadIdx.x;
    const int kc = blockIdx.y;                    // 0..15
    if (d >= DM) return;
    float s[NB];
    #pragma unroll
    for (int b = 0; b < NB; ++b) s[b] = 0.f;
    const int k0 = kc * 125;
    for (int k = k0; k < k0 + 125; ++k) {
        float wv = Wo[(size_t)k * DM + d];
        #pragma unroll
        for (int b = 0; b < NB; ++b) s[b] = fmaf(sy[b * EDP + k], wv, s[b]);
    }
    #pragma unroll
    for (int b = 0; b < NB; ++b) ep[(size_t)(b * 16 + kc) * DMP + d] = s[b];
}
__global__ void e_red(const float* __restrict__ ep, const float* __restrict__ xm,
                      float* __restrict__ e) {
    const int d = blockIdx.x * 256 + threadIdx.x;
    const int b = blockIdx.y;
    if (d >= DM) return;
    float s = xm[b * DMP + d];
    #pragma unroll
    for (int kc = 0; kc < 16; ++kc) s += ep[(size_t)(b * 16 + kc) * DMP + d];
    e[b * DMP + d] = s;
}

// ---- fc: all batches per block (8 chunks of 125) ---------------------------
__global__ void fc_part(const float* __restrict__ e, const float* __restrict__ Wfc,
                        float* __restrict__ fp) {
    const int d = blockIdx.x * 256 + threadIdx.x;
    const int kc = blockIdx.y;                    // 0..7
    if (d >= DM) return;
    float s[NB];
    #pragma unroll
    for (int b = 0; b < NB; ++b) s[b] = 0.f;
    const int k0 = kc * 125;
    for (int k = k0; k < k0 + 125; ++k) {
        float wv = Wfc[(size_t)k * DM + d];
        #pragma unroll
        for (int b = 0; b < NB; ++b) s[b] = fmaf(e[b * DMP + k], wv, s[b]);
    }
    #pragma unroll
    for (int b = 0; b < NB; ++b) fp[(size_t)(b * 8 + kc) * DMP + d] = s[b];
}
__global__ void fc_red(const float* __restrict__ fp, const float* __restrict__ bfc,
                       float* __restrict__ out) {
    const int d = blockIdx.x * 256 + threadIdx.x;
    const int b = blockIdx.y;
    if (d >= DM) return;
    float s = bfc[d];
    #pragma unroll
    for (int kc = 0; kc < 8; ++kc) s += fp[(size_t)(b * 8 + kc) * DMP + d];
    float t = tanhf(s);
    out[b * DM + d] = (t > 0.f) ? t : expm1f(t);
}

// ---- heads: all batches per block (8 chunks of 125) ------------------------
__global__ void head_part(const float* __restrict__ hout, const float* __restrict__ Wmu,
                          const float* __restrict__ Wsig, float* __restrict__ hp) {
    const int o = threadIdx.x;                    // 64
    const int kc = blockIdx.x;                    // 0..7
    float sm[NB], sg[NB];
    #pragma unroll
    for (int b = 0; b < NB; ++b) { sm[b] = 0.f; sg[b] = 0.f; }
    const int k0 = kc * 125;
    for (int k = k0; k < k0 + 125; ++k) {
        float wm = Wmu[k * 64 + o], ws = Wsig[k * 64 + o];
        #pragma unroll
        for (int b = 0; b < NB; ++b) {
            float hv = hout[b * DM + k];
            sm[b] = fmaf(hv, wm, sm[b]);
            sg[b] = fmaf(hv, ws, sg[b]);
        }
    }
    #pragma unroll
    for (int b = 0; b < NB; ++b) {
        hp[(size_t)(b * 8 + kc) * 128 + o]      = sm[b];
        hp[(size_t)(b * 8 + kc) * 128 + 64 + o] = sg[b];
    }
}
__global__ void head_red(const float* __restrict__ hp, const float* __restrict__ bmu,
                         const float* __restrict__ bsig, float* __restrict__ out) {
    const int o = threadIdx.x;                    // 64
    const int b = blockIdx.x;
    float sm = bmu[o], sg = bsig[o];
    #pragma unroll
    for (int kc = 0; kc < 8; ++kc) {
        sm += hp[(size_t)(b * 8 + kc) * 128 + o];
        sg += hp[(size_t)(b * 8 + kc) * 128 + 64 + o];
    }
    out[8000 + b * 64 + o] = sm;
    float el = (sg > 0.f) ? sg : expm1f(sg);
    out[8512 + b * 64 + o] = el + 1.f + 1e-14f;
}

extern "C" void kernel_launch(void* const* d_in, const int* in_sizes, int n_in,
                              void* d_out, int out_size, void* d_ws, size_t ws_size,
                              hipStream_t stream) {
    const float* x       = (const float*)d_in[0];
    const float* w_norm  = (const float*)d_in[1];
    const float* W_in    = (const float*)d_in[2];
    const float* conv_w  = (const float*)d_in[3];
    const float* conv_b  = (const float*)d_in[4];
    const float* W_xproj = (const float*)d_in[5];
    const float* W_dt    = (const float*)d_in[6];
    const float* b_dt    = (const float*)d_in[7];
    const float* A_log   = (const float*)d_in[8];
    const float* Dp      = (const float*)d_in[9];
    const float* W_outp  = (const float*)d_in[10];
    const float* W_fc    = (const float*)d_in[11];
    const float* b_fc    = (const float*)d_in[12];
    const float* W_mu    = (const float*)d_in[13];
    const float* b_mu    = (const float*)d_in[14];
    const float* W_sig   = (const float*)d_in[15];
    const float* b_sig   = (const float*)d_in[16];
    float* out = (float*)d_out;

    char* p = (char*)d_ws;
    auto al = [](size_t b) { return (b + 255) & ~(size_t)255; };
    auto carve = [&](size_t bytes) { char* r = p; p += al(bytes); return r; };

    // small buffers (always)
    u16*   Wt    = (u16*)carve((size_t)N1 * K1 * 2);       // 8 MiB
    u16*   WxT   = (u16*)carve((size_t)128 * EDP * 2);
    u16*   WdtT  = (u16*)carve((size_t)EDP * 64 * 2);
    float* syb   = (float*)carve((size_t)NB * EDP * 4);
    float* xmb   = (float*)carve((size_t)NB * DMP * 4);
    float* eb    = (float*)carve((size_t)NB * DMP * 4);
    float* mpart = (float*)carve((size_t)NB * MXCH * DMP * 4);   // 1 MiB
    float* ep    = (float*)carve((size_t)NB * 16 * DMP * 4);     // 512 KiB
    float* fp    = (float*)carve((size_t)NB * 8 * DMP * 4);      // 256 KiB
    float* hp    = (float*)carve((size_t)NB * 8 * 128 * 4);      // 32 KiB

    // group-size selection: largest g in {8,4,2,1} whose big buffers fit ws
    size_t used = (size_t)(p - (char*)d_ws);
    size_t unit = al((size_t)LSEQ * DMP * 2) + 3 * al((size_t)LSEQ * EDP * 2)
                + al((size_t)LSEQ * 64 * 2) + al((size_t)LSEQ * 16 * 4);   // ~28.4 MiB/batch
    size_t avail = (ws_size > used) ? ws_size - used : 0;
    int g = 8;
    while (g > 1 && (size_t)g * unit > avail) g >>= 1;
    const int M = g * LSEQ;

    // big buffers, sized for one group of g batches (lifetime-aliased)
    char*  reg0 = carve((size_t)M * DMP * 2);          // g*4 MiB: xn, later summaries
    char*  reg1 = carve((size_t)M * EDP * 2);          // g*8 MiB: xcr, later dlt
    u16*   zsb  = (u16*)carve((size_t)M * EDP * 2);    // g*8 MiB
    u16*   xca  = (u16*)carve((size_t)M * EDP * 2);    // g*8 MiB
    u16*   dtb  = (u16*)carve((size_t)M * 64 * 2);
    float* bcb  = (float*)carve((size_t)M * 16 * 4);

    u16*   xn   = (u16*)reg0;
    const size_t MB1 = (size_t)1 << 20;                 // per-batch summary = 1 MiB each
    float* Pb   = (float*)reg0;
    float* wbuf = (float*)(reg0 + (size_t)g * MB1);
    float* hlb  = (float*)(reg0 + (size_t)2 * g * MB1);
    float* accb = (float*)(reg0 + (size_t)3 * g * MB1); // 3.125g MiB <= 4g MiB region
    u16*   xcr  = (u16*)reg1;
    u16*   dlt  = (u16*)reg1;

    // prologue (batch-independent)
    meanx_part <<<dim3(1, NB, MXCH), 256, 0, stream>>>(x, mpart);
    meanx_red  <<<dim3(4, NB), 256, 0, stream>>>(mpart, xmb);
    packWt_kernel<<<dim3(128, 32), dim3(32, 8), 0, stream>>>(W_in, Wt);
    packWxT_kernel<<<1024, 256, 0, stream>>>(W_xproj, WxT);
    packWdtT_kernel<<<512, 256, 0, stream>>>(W_dt, WdtT);

    for (int b0 = 0; b0 < NB; b0 += g) {
        const float* xg = x + (size_t)b0 * LSEQ * DM;
        rms_kernel <<<M, 256, 0, stream>>>(xg, w_norm, xn);
        gemm_bt<0><<<dim3(N1 / 128, M / 128), 256, 0, stream>>>(xn, Wt, K1, K1, K1 / 32,
                                                                xcr, zsb, nullptr, nullptr);
        conv_kernel<<<M, 256, 0, stream>>>(xcr, conv_w, conv_b, xca);
        gemm_bt<1><<<dim3(1, M / 128), 256, 0, stream>>>(xca, WxT, EDP, EDP, EDP / 32,
                                                         dtb, nullptr, bcb, nullptr);
        gemm_bt<2><<<dim3(EDP / 128, M / 128), 256, 0, stream>>>(dtb, WdtT, 64, 64, 2,
                                                                 dlt, nullptr, nullptr, b_dt);
        scan1_kernel<<<dim3(EDP / 256, g, CHK), 256, 0, stream>>>(dlt, xca, zsb, bcb,
                                                                  A_log, Dp, Pb, wbuf, hlb, accb);
        scan2_kernel<<<dim3(EDP / 256, g), 256, 0, stream>>>(Pb, wbuf, hlb, accb,
                                                             syb + (size_t)b0 * EDP);
    }

    e_part <<<dim3(4, 16), 256, 0, stream>>>(syb, W_outp, ep);
    e_red  <<<dim3(4, NB), 256, 0, stream>>>(ep, xmb, eb);
    fc_part<<<dim3(4, 8), 256, 0, stream>>>(eb, W_fc, fp);
    fc_red <<<dim3(4, NB), 256, 0, stream>>>(fp, b_fc, out);
    head_part<<<8, 64, 0, stream>>>(out, W_mu, W_sig, hp);
    head_red <<<NB, 64, 0, stream>>>(hp, b_mu, b_sig, out);
}

// Round 14
// 913.083 us; speedup vs baseline: 2.3703x; 1.0087x over previous
//
#include <hip/hip_runtime.h>

#define DM    1000
#define DMP   1024
#define ED    2000
#define EDP   2048
#define NST   8
#define LSEQ  2048
#define NB    8
#define MTOT  16384     // NB*LSEQ
#define N1    4096      // gemm1 padded N (2*ED)
#define K1    1024      // gemm1 padded K
#define CHK   16        // scan chunks
#define CLEN  (LSEQ/CHK)
#define MXCH  32        // meanx L-chunks
#define KSPL  8         // xproj split-K factor

typedef unsigned short u16;
typedef __attribute__((ext_vector_type(4))) float f32x4;
typedef __attribute__((ext_vector_type(8))) short bf16x8;
typedef __attribute__((ext_vector_type(4))) unsigned short u16x4;

__device__ __forceinline__ u16 f2bf(float f) {
    union { float f; unsigned u; } v; v.f = f;
    unsigned r = v.u + 0x7FFFu + ((v.u >> 16) & 1u);
    return (u16)(r >> 16);
}
__device__ __forceinline__ float bf2f(u16 h) {
    union { unsigned u; float f; } v; v.u = ((unsigned)h) << 16; return v.f;
}
__device__ __forceinline__ float siluf(float x) { return x / (1.f + __expf(-x)); }

// ---------------- mean over L of x: partial, float4 ----------------
__global__ void meanx_part(const float* __restrict__ x, float* __restrict__ part) {
    const int t = threadIdx.x;                      // 0..255 -> d4
    const int b = blockIdx.y;
    const int c = blockIdx.z;
    float4 s = make_float4(0.f, 0.f, 0.f, 0.f);
    if (t < 250) {
        const int l0 = c * (LSEQ / MXCH);
        for (int l = l0; l < l0 + LSEQ / MXCH; ++l) {
            float4 v = ((const float4*)(x + ((size_t)b * LSEQ + l) * DM))[t];
            s.x += v.x; s.y += v.y; s.z += v.z; s.w += v.w;
        }
    }
    ((float4*)(part + (size_t)(b * MXCH + c) * DMP))[t] = s;
}
__global__ void meanx_red(const float* __restrict__ part, float* __restrict__ xm) {
    const int d = blockIdx.x * 256 + threadIdx.x;
    const int b = blockIdx.y;
    float s = 0.f;
    #pragma unroll
    for (int c = 0; c < MXCH; ++c) s += part[(size_t)(b * MXCH + c) * DMP + d];
    xm[b * DMP + d] = s * (1.f / LSEQ);
}

// ---------------- RMSNorm -> bf16 padded, float4 in / ushort4 out ----------
__global__ void rms_kernel(const float* __restrict__ x, const float* __restrict__ w,
                           u16* __restrict__ xn) {
    const int row = blockIdx.x;
    const int tid = threadIdx.x;
    const float* xr = x + (size_t)row * DM;
    float ss = 0.f;
    if (tid < 250) {
        float4 v = ((const float4*)xr)[tid];
        ss = v.x * v.x + v.y * v.y + v.z * v.z + v.w * v.w;
    }
    #pragma unroll
    for (int o = 32; o > 0; o >>= 1) ss += __shfl_xor(ss, o);
    __shared__ float red[4];
    if ((tid & 63) == 0) red[tid >> 6] = ss;
    __syncthreads();
    float tot = red[0] + red[1] + red[2] + red[3];
    float sc = rsqrtf(tot * (1.f / DM) + 1e-5f);
    u16x4 o4 = (u16x4){0, 0, 0, 0};
    if (tid < 250) {
        float4 v = ((const float4*)xr)[tid];
        float4 g = ((const float4*)w)[tid];
        o4[0] = f2bf(v.x * sc * g.x); o4[1] = f2bf(v.y * sc * g.y);
        o4[2] = f2bf(v.z * sc * g.z); o4[3] = f2bf(v.w * sc * g.w);
    }
    *(u16x4*)&xn[(size_t)row * DMP + 4 * tid] = o4;
}

// ---------------- weight packs ----------------
__global__ void packWt_kernel(const float* __restrict__ W, u16* __restrict__ Wt) {
    __shared__ float t[32][33];
    int nt = blockIdx.x * 32, kt = blockIdx.y * 32;
    int tx = threadIdx.x, ty = threadIdx.y;   // 32 x 8
    for (int j = 0; j < 32; j += 8) {
        int k = kt + ty + j, n = nt + tx;
        t[ty + j][tx] = (k < DM && n < 2 * ED) ? W[(size_t)k * (2 * ED) + n] : 0.f;
    }
    __syncthreads();
    for (int j = 0; j < 32; j += 8) {
        int n = nt + ty + j, k = kt + tx;
        Wt[(size_t)n * K1 + k] = f2bf(t[tx][ty + j]);
    }
}
__global__ void packWxT_kernel(const float* __restrict__ W, u16* __restrict__ WxT) {
    int gid = blockIdx.x * 256 + threadIdx.x;       // 128*2048
    int n = gid >> 11, k = gid & (EDP - 1);
    int c = (n < 63) ? n : ((n >= 64 && n < 80) ? n - 1 : -1);
    float v = (c >= 0 && k < ED) ? W[(size_t)k * 79 + c] : 0.f;
    WxT[gid] = f2bf(v);
}
__global__ void packWdtT_kernel(const float* __restrict__ W, u16* __restrict__ Wt) {
    int gid = blockIdx.x * 256 + threadIdx.x;       // 2048*64
    int n = gid >> 6, k = gid & 63;
    float v = (n < ED && k < 63) ? W[(size_t)k * ED + n] : 0.f;
    Wt[gid] = f2bf(v);
}

// ---------------- MFMA GEMM body: C[M,N] = A[M,K] * Bt[N,K]^T ---------------
// MODE 0: n<2000 -> o0 raw bf16; 2000..3999 -> o1 silu bf16
// MODE 1: split-K partial writer: of[kz][row][128] fp32 (kz = blockIdx.z)
// MODE 2: n<2000 -> o0 = bf16(softplus(v + bias[n]))
template<int MODE>
__device__ __forceinline__ void gemm_body(const u16* __restrict__ A, const u16* __restrict__ Bt,
                                          int lda, int ldb, int ksteps,
                                          u16* __restrict__ o0, u16* __restrict__ o1,
                                          float* __restrict__ of, const float* __restrict__ bias) {
    __shared__ u16 As[128 * 32];
    __shared__ u16 Bs[128 * 32];
    const int tid = threadIdx.x;
    const int wv = tid >> 6, ln = tid & 63;
    const int mbase = blockIdx.y << 7, nbase = blockIdx.x << 7;
    const int kz = (MODE == 1) ? blockIdx.z : 0;
    const int wm = (wv >> 1) << 6, wn = (wv & 1) << 6;
    const int fr = ln & 15, fo = ln >> 4;

    f32x4 acc[4][4];
    #pragma unroll
    for (int i = 0; i < 4; ++i)
        #pragma unroll
        for (int j = 0; j < 4; ++j) acc[i][j] = (f32x4){0.f, 0.f, 0.f, 0.f};

    for (int ks = kz * ksteps; ks < kz * ksteps + ksteps; ++ks) {
        const int kt = ks << 5;
        __syncthreads();
        #pragma unroll
        for (int i = 0; i < 2; ++i) {
            int c = (wv << 7) + (i << 6) + ln;            // chunk id 0..511
            const u16* ga = A + (size_t)(mbase + (c >> 2)) * lda + kt + ((c & 3) << 3);
            __builtin_amdgcn_global_load_lds(
                (const __attribute__((address_space(1))) void*)ga,
                (__attribute__((address_space(3))) void*)&As[((wv << 7) + (i << 6)) * 8],
                16, 0, 0);
            const u16* gb = Bt + (size_t)(nbase + (c >> 2)) * ldb + kt + ((c & 3) << 3);
            __builtin_amdgcn_global_load_lds(
                (const __attribute__((address_space(1))) void*)gb,
                (__attribute__((address_space(3))) void*)&Bs[((wv << 7) + (i << 6)) * 8],
                16, 0, 0);
        }
        asm volatile("s_waitcnt vmcnt(0)" ::: "memory");
        __syncthreads();

        bf16x8 af[4], bg[4];
        #pragma unroll
        for (int i = 0; i < 4; ++i) {
            af[i] = *(const bf16x8*)&As[((wm + (i << 4) + fr) << 5) + (fo << 3)];
            bg[i] = *(const bf16x8*)&Bs[((wn + (i << 4) + fr) << 5) + (fo << 3)];
        }
        #pragma unroll
        for (int i = 0; i < 4; ++i)
            #pragma unroll
            for (int j = 0; j < 4; ++j)
                acc[i][j] = __builtin_amdgcn_mfma_f32_16x16x32_bf16(af[i], bg[j], acc[i][j], 0, 0, 0);
    }

    const int Mrows = gridDim.y << 7;
    #pragma unroll
    for (int i = 0; i < 4; ++i) {
        #pragma unroll
        for (int j = 0; j < 4; ++j) {
            int col = nbase + wn + (j << 4) + fr;
            #pragma unroll
            for (int r = 0; r < 4; ++r) {
                int row = mbase + wm + (i << 4) + (fo << 2) + r;
                float v = acc[i][j][r];
                if (MODE == 0) {
                    if (col < ED)            o0[(size_t)row * EDP + col] = f2bf(v);
                    else if (col < 2 * ED)   o1[(size_t)row * EDP + (col - ED)] = f2bf(siluf(v));
                } else if (MODE == 1) {
                    of[((size_t)kz * Mrows + row) * 128 + col] = v;
                } else {
                    if (col < ED) {
                        float s = v + bias[col];
                        float sp = (s > 20.f) ? s : log1pf(__expf(s));
                        o0[(size_t)row * EDP + col] = f2bf(sp);
                    }
                }
            }
        }
    }
}

__global__ __launch_bounds__(256, 2)
void gemm_in(const u16* __restrict__ A, const u16* __restrict__ Bt, int lda, int ldb,
             int ksteps, u16* __restrict__ o0, u16* __restrict__ o1) {
    gemm_body<0>(A, Bt, lda, ldb, ksteps, o0, o1, nullptr, nullptr);
}
__global__ __launch_bounds__(256, 2)
void gemm_xproj(const u16* __restrict__ A, const u16* __restrict__ Bt, int lda, int ldb,
                int ksteps, float* __restrict__ of) {
    gemm_body<1>(A, Bt, lda, ldb, ksteps, nullptr, nullptr, of, nullptr);
}
__global__ __launch_bounds__(256, 2)
void gemm_dt(const u16* __restrict__ A, const u16* __restrict__ Bt, int lda, int ldb,
             int ksteps, u16* __restrict__ o0, const float* __restrict__ bias) {
    gemm_body<2>(A, Bt, lda, ldb, ksteps, o0, nullptr, nullptr, bias);
}

// ---- xproj split-K reduce: sum partials, emit dt (bf16) + B/C (fp32) -------
__global__ void xproj_red(const float* __restrict__ part, int Mrows,
                          u16* __restrict__ dtb, float* __restrict__ bcb) {
    const int t = threadIdx.x;
    const int row = blockIdx.x * 2 + (t >> 7);
    const int col = t & 127;
    float s = 0.f;
    #pragma unroll
    for (int kc = 0; kc < KSPL; ++kc)
        s += part[((size_t)kc * Mrows + row) * 128 + col];
    if (col < 64)       dtb[(size_t)row * 64 + col] = f2bf(s);
    else if (col < 80)  bcb[(size_t)row * 16 + (col - 64)] = s;
}

// ---------------- depthwise causal conv, 8 channels/thread (short8) --------
__global__ void conv_kernel(const u16* __restrict__ xcr, const float* __restrict__ cw,
                            const float* __restrict__ cb, u16* __restrict__ xca) {
    const int e8 = threadIdx.x;                   // 0..255
    const int row = blockIdx.x;
    const int ed0 = e8 * 8;
    const size_t base = (size_t)row * EDP + ed0;
    if (ed0 >= ED) {
        *(bf16x8*)&xca[base] = (bf16x8){0, 0, 0, 0, 0, 0, 0, 0};
        return;
    }
    const int l = row & (LSEQ - 1);
    float wv[8][4], acc[8];
    #pragma unroll
    for (int t = 0; t < 8; ++t) {
        float4 q = ((const float4*)cw)[ed0 + t];
        wv[t][0] = q.x; wv[t][1] = q.y; wv[t][2] = q.z; wv[t][3] = q.w;
    }
    {
        float4 b0 = ((const float4*)cb)[e8 * 2];
        float4 b1 = ((const float4*)cb)[e8 * 2 + 1];
        acc[0] = b0.x; acc[1] = b0.y; acc[2] = b0.z; acc[3] = b0.w;
        acc[4] = b1.x; acc[5] = b1.y; acc[6] = b1.z; acc[7] = b1.w;
    }
    #pragma unroll
    for (int j = 0; j < 4; ++j) {
        if (l - 3 + j >= 0) {
            bf16x8 r = *(const bf16x8*)&xcr[(size_t)(row - 3 + j) * EDP + ed0];
            #pragma unroll
            for (int t = 0; t < 8; ++t)
                acc[t] = fmaf(wv[t][j], bf2f((u16)r[t]), acc[t]);
        }
    }
    bf16x8 o;
    #pragma unroll
    for (int t = 0; t < 8; ++t) o[t] = (short)f2bf(siluf(acc[t]));
    *(bf16x8*)&xca[base] = o;
}

// ---------------- selective scan pass 1: per-chunk local scan --------------
__global__ void scan1_kernel(const u16* __restrict__ dlt, const u16* __restrict__ xca,
                             const u16* __restrict__ zs, const float* __restrict__ bc,
                             const float* __restrict__ A_log, const float* __restrict__ Dp,
                             float* __restrict__ Pb, float* __restrict__ wb,
                             float* __restrict__ hlb, float* __restrict__ accb) {
    const int ed = blockIdx.x * 256 + threadIdx.x;
    const int b = blockIdx.y;
    const int c = blockIdx.z;
    const int edc = (ed < ED) ? ed : (ED - 1);
    float An[NST];
    #pragma unroll
    for (int n = 0; n < NST; ++n) An[n] = -__expf(A_log[edc * NST + n]);
    const float dpv = Dp[edc];
    float g[NST], cd[NST], w[NST];
    #pragma unroll
    for (int n = 0; n < NST; ++n) { g[n] = 0.f; cd[n] = 1.f; w[n] = 0.f; }
    float acc = 0.f;

    const size_t rbase = (size_t)b * LSEQ + (size_t)c * CLEN;
    const float4* bc4 = (const float4*)bc;
    size_t i0 = rbase * EDP + ed;
    float dv = bf2f(dlt[i0]), xv = bf2f(xca[i0]), zv = bf2f(zs[i0]);
    float4 q0 = bc4[rbase * 4 + 0], q1 = bc4[rbase * 4 + 1];
    float4 q2 = bc4[rbase * 4 + 2], q3 = bc4[rbase * 4 + 3];

    for (int l = 0; l < CLEN; ++l) {
        float dv2 = 0.f, xv2 = 0.f, zv2 = 0.f;
        float4 p0 = make_float4(0.f,0.f,0.f,0.f), p1 = p0, p2 = p0, p3 = p0;
        if (l + 1 < CLEN) {
            size_t i2 = (rbase + l + 1) * EDP + ed;
            dv2 = bf2f(dlt[i2]); xv2 = bf2f(xca[i2]); zv2 = bf2f(zs[i2]);
            p0 = bc4[(rbase + l + 1) * 4 + 0]; p1 = bc4[(rbase + l + 1) * 4 + 1];
            p2 = bc4[(rbase + l + 1) * 4 + 2]; p3 = bc4[(rbase + l + 1) * 4 + 3];
        }
        const float Bv[8] = {q0.x,q0.y,q0.z,q0.w,q1.x,q1.y,q1.z,q1.w};
        const float Cv[8] = {q2.x,q2.y,q2.z,q2.w,q3.x,q3.y,q3.z,q3.w};
        float dx = dv * xv;
        float yl = 0.f;
        #pragma unroll
        for (int n = 0; n < NST; ++n) {
            float dA = __expf(dv * An[n]);
            cd[n] *= dA;
            g[n] = fmaf(g[n], dA, dx * Bv[n]);
            yl = fmaf(g[n], Cv[n], yl);
            w[n] = fmaf(zv * Cv[n], cd[n], w[n]);
        }
        acc = fmaf(yl + dpv * xv, zv, acc);
        dv = dv2; xv = xv2; zv = zv2; q0 = p0; q1 = p1; q2 = p2; q3 = p3;
    }
    const size_t o = ((size_t)(b * CHK + c) * NST) * EDP + ed;
    #pragma unroll
    for (int n = 0; n < NST; ++n) {
        Pb [o + (size_t)n * EDP] = cd[n];
        wb [o + (size_t)n * EDP] = w[n];
        hlb[o + (size_t)n * EDP] = g[n];
    }
    accb[(size_t)(b * CHK + c) * EDP + ed] = acc;
}

// ---------------- selective scan pass 2 ------------------------------------
__global__ void scan2_kernel(const float* __restrict__ Pb, const float* __restrict__ wb,
                             const float* __restrict__ hlb, const float* __restrict__ accb,
                             float* __restrict__ sy) {
    const int ed = blockIdx.x * 256 + threadIdx.x;
    const int b = blockIdx.y;
    float h[NST];
    #pragma unroll
    for (int n = 0; n < NST; ++n) h[n] = 0.f;
    float acc = 0.f;
    #pragma unroll
    for (int c = 0; c < CHK; ++c) {
        const size_t o = ((size_t)(b * CHK + c) * NST) * EDP + ed;
        acc += accb[(size_t)(b * CHK + c) * EDP + ed];
        #pragma unroll
        for (int n = 0; n < NST; ++n) acc = fmaf(wb[o + (size_t)n * EDP], h[n], acc);
        #pragma unroll
        for (int n = 0; n < NST; ++n)
            h[n] = fmaf(Pb[o + (size_t)n * EDP], h[n], hlb[o + (size_t)n * EDP]);
    }
    if (ed < ED) sy[b * EDP + ed] = acc * (1.f / LSEQ);
}

// ---- e: all batches per block, weights streamed once (16 chunks of 125) ----
__global__ void e_part(const float* __restrict__ sy, const float* __restrict__ Wo,
                       float* __restrict__ ep) {
    const int d = blockIdx.x * 256 + threadIdx.x;
    const int kc = blockIdx.y;                    // 0..15
    if (d >= DM) return;
    float s[NB];
    #pragma unroll
    for (int b = 0; b < NB; ++b) s[b] = 0.f;
    const int k0 = kc * 125;
    for (int k = k0; k < k0 + 125; ++k) {
        float wv = Wo[(size_t)k * DM + d];
        #pragma unroll
        for (int b = 0; b < NB; ++b) s[b] = fmaf(sy[b * EDP + k], wv, s[b]);
    }
    #pragma unroll
    for (int b = 0; b < NB; ++b) ep[(size_t)(b * 16 + kc) * DMP + d] = s[b];
}
__global__ void e_red(const float* __restrict__ ep, const float* __restrict__ xm,
                      float* __restrict__ e) {
    const int d = blockIdx.x * 256 + threadIdx.x;
    const int b = blockIdx.y;
    if (d >= DM) return;
    float s = xm[b * DMP + d];
    #pragma unroll
    for (int kc = 0; kc < 16; ++kc) s += ep[(size_t)(b * 16 + kc) * DMP + d];
    e[b * DMP + d] = s;
}

// ---- fc: all batches per block (8 chunks of 125) ---------------------------
__global__ void fc_part(const float* __restrict__ e, const float* __restrict__ Wfc,
                        float* __restrict__ fp) {
    const int d = blockIdx.x * 256 + threadIdx.x;
    const int kc = blockIdx.y;                    // 0..7
    if (d >= DM) return;
    float s[NB];
    #pragma unroll
    for (int b = 0; b < NB; ++b) s[b] = 0.f;
    const int k0 = kc * 125;
    for (int k = k0; k < k0 + 125; ++k) {
        float wv = Wfc[(size_t)k * DM + d];
        #pragma unroll
        for (int b = 0; b < NB; ++b) s[b] = fmaf(e[b * DMP + k], wv, s[b]);
    }
    #pragma unroll
    for (int b = 0; b < NB; ++b) fp[(size_t)(b * 8 + kc) * DMP + d] = s[b];
}
__global__ void fc_red(const float* __restrict__ fp, const float* __restrict__ bfc,
                       float* __restrict__ out) {
    const int d = blockIdx.x * 256 + threadIdx.x;
    const int b = blockIdx.y;
    if (d >= DM) return;
    float s = bfc[d];
    #pragma unroll
    for (int kc = 0; kc < 8; ++kc) s += fp[(size_t)(b * 8 + kc) * DMP + d];
    float t = tanhf(s);
    out[b * DM + d] = (t > 0.f) ? t : expm1f(t);
}

// ---- heads: all batches per block (8 chunks of 125) ------------------------
__global__ void head_part(const float* __restrict__ hout, const float* __restrict__ Wmu,
                          const float* __restrict__ Wsig, float* __restrict__ hp) {
    const int o = threadIdx.x;                    // 64
    const int kc = blockIdx.x;                    // 0..7
    float sm[NB], sg[NB];
    #pragma unroll
    for (int b = 0; b < NB; ++b) { sm[b] = 0.f; sg[b] = 0.f; }
    const int k0 = kc * 125;
    for (int k = k0; k < k0 + 125; ++k) {
        float wm = Wmu[k * 64 + o], ws = Wsig[k * 64 + o];
        #pragma unroll
        for (int b = 0; b < NB; ++b) {
            float hv = hout[b * DM + k];
            sm[b] = fmaf(hv, wm, sm[b]);
            sg[b] = fmaf(hv, ws, sg[b]);
        }
    }
    #pragma unroll
    for (int b = 0; b < NB; ++b) {
        hp[(size_t)(b * 8 + kc) * 128 + o]      = sm[b];
        hp[(size_t)(b * 8 + kc) * 128 + 64 + o] = sg[b];
    }
}
__global__ void head_red(const float* __restrict__ hp, const float* __restrict__ bmu,
                         const float* __restrict__ bsig, float* __restrict__ out) {
    const int o = threadIdx.x;                    // 64
    const int b = blockIdx.x;
    float sm = bmu[o], sg = bsig[o];
    #pragma unroll
    for (int kc = 0; kc < 8; ++kc) {
        sm += hp[(size_t)(b * 8 + kc) * 128 + o];
        sg += hp[(size_t)(b * 8 + kc) * 128 + 64 + o];
    }
    out[8000 + b * 64 + o] = sm;
    float el = (sg > 0.f) ? sg : expm1f(sg);
    out[8512 + b * 64 + o] = el + 1.f + 1e-14f;
}

extern "C" void kernel_launch(void* const* d_in, const int* in_sizes, int n_in,
                              void* d_out, int out_size, void* d_ws, size_t ws_size,
                              hipStream_t stream) {
    const float* x       = (const float*)d_in[0];
    const float* w_norm  = (const float*)d_in[1];
    const float* W_in    = (const float*)d_in[2];
    const float* conv_w  = (const float*)d_in[3];
    const float* conv_b  = (const float*)d_in[4];
    const float* W_xproj = (const float*)d_in[5];
    const float* W_dt    = (const float*)d_in[6];
    const float* b_dt    = (const float*)d_in[7];
    const float* A_log   = (const float*)d_in[8];
    const float* Dp      = (const float*)d_in[9];
    const float* W_outp  = (const float*)d_in[10];
    const float* W_fc    = (const float*)d_in[11];
    const float* b_fc    = (const float*)d_in[12];
    const float* W_mu    = (const float*)d_in[13];
    const float* b_mu    = (const float*)d_in[14];
    const float* W_sig   = (const float*)d_in[15];
    const float* b_sig   = (const float*)d_in[16];
    float* out = (float*)d_out;

    char* p = (char*)d_ws;
    auto al = [](size_t b) { return (b + 255) & ~(size_t)255; };
    auto carve = [&](size_t bytes) { char* r = p; p += al(bytes); return r; };

    // small buffers (always)
    u16*   Wt    = (u16*)carve((size_t)N1 * K1 * 2);       // 8 MiB
    u16*   WxT   = (u16*)carve((size_t)128 * EDP * 2);
    u16*   WdtT  = (u16*)carve((size_t)EDP * 64 * 2);
    float* syb   = (float*)carve((size_t)NB * EDP * 4);
    float* xmb   = (float*)carve((size_t)NB * DMP * 4);
    float* eb    = (float*)carve((size_t)NB * DMP * 4);
    float* mpart = (float*)carve((size_t)NB * MXCH * DMP * 4);   // 1 MiB
    float* ep    = (float*)carve((size_t)NB * 16 * DMP * 4);     // 512 KiB
    float* fp    = (float*)carve((size_t)NB * 8 * DMP * 4);      // 256 KiB
    float* hp    = (float*)carve((size_t)NB * 8 * 128 * 4);      // 32 KiB

    // group-size selection: largest g in {8,4,2,1} whose big buffers fit ws
    size_t used = (size_t)(p - (char*)d_ws);
    size_t unit = al((size_t)LSEQ * DMP * 2) + 3 * al((size_t)LSEQ * EDP * 2)
                + al((size_t)LSEQ * 64 * 2) + al((size_t)LSEQ * 16 * 4);   // ~28.4 MiB/batch
    size_t avail = (ws_size > used) ? ws_size - used : 0;
    int g = 8;
    while (g > 1 && (size_t)g * unit > avail) g >>= 1;
    const int M = g * LSEQ;

    // big buffers, sized for one group of g batches (lifetime-aliased)
    char*  reg0 = carve((size_t)M * DMP * 2);          // g*4 MiB: xn, later summaries
    char*  reg1 = carve((size_t)M * EDP * 2);          // g*8 MiB: xcr -> xproj partials -> dlt
    u16*   zsb  = (u16*)carve((size_t)M * EDP * 2);    // g*8 MiB
    u16*   xca  = (u16*)carve((size_t)M * EDP * 2);    // g*8 MiB
    u16*   dtb  = (u16*)carve((size_t)M * 64 * 2);
    float* bcb  = (float*)carve((size_t)M * 16 * 4);

    u16*   xn   = (u16*)reg0;
    const size_t MB1 = (size_t)1 << 20;                 // per-batch summary = 1 MiB each
    float* Pb   = (float*)reg0;
    float* wbuf = (float*)(reg0 + (size_t)g * MB1);
    float* hlb  = (float*)(reg0 + (size_t)2 * g * MB1);
    float* accb = (float*)(reg0 + (size_t)3 * g * MB1); // 3.125g MiB <= 4g MiB region
    u16*   xcr  = (u16*)reg1;
    float* xpart = (float*)reg1;                        // KSPL*M*128*4 = M*4096 B = reg1 size
    u16*   dlt  = (u16*)reg1;

    // prologue (batch-independent)
    meanx_part <<<dim3(1, NB, MXCH), 256, 0, stream>>>(x, mpart);
    meanx_red  <<<dim3(4, NB), 256, 0, stream>>>(mpart, xmb);
    packWt_kernel<<<dim3(128, 32), dim3(32, 8), 0, stream>>>(W_in, Wt);
    packWxT_kernel<<<1024, 256, 0, stream>>>(W_xproj, WxT);
    packWdtT_kernel<<<512, 256, 0, stream>>>(W_dt, WdtT);

    for (int b0 = 0; b0 < NB; b0 += g) {
        const float* xg = x + (size_t)b0 * LSEQ * DM;
        rms_kernel <<<M, 256, 0, stream>>>(xg, w_norm, xn);
        gemm_in   <<<dim3(N1 / 128, M / 128), 256, 0, stream>>>(xn, Wt, K1, K1, K1 / 32,
                                                                xcr, zsb);
        conv_kernel<<<M, 256, 0, stream>>>(xcr, conv_w, conv_b, xca);
        gemm_xproj<<<dim3(1, M / 128, KSPL), 256, 0, stream>>>(xca, WxT, EDP, EDP,
                                                               (EDP / 32) / KSPL, xpart);
        xproj_red <<<M / 2, 256, 0, stream>>>(xpart, M, dtb, bcb);
        gemm_dt   <<<dim3(EDP / 128, M / 128), 256, 0, stream>>>(dtb, WdtT, 64, 64, 2,
                                                                 dlt, b_dt);
        scan1_kernel<<<dim3(EDP / 256, g, CHK), 256, 0, stream>>>(dlt, xca, zsb, bcb,
                                                                  A_log, Dp, Pb, wbuf, hlb, accb);
        scan2_kernel<<<dim3(EDP / 256, g), 256, 0, stream>>>(Pb, wbuf, hlb, accb,
                                                             syb + (size_t)b0 * EDP);
    }

    e_part <<<dim3(4, 16), 256, 0, stream>>>(syb, W_outp, ep);
    e_red  <<<dim3(4, NB), 256, 0, stream>>>(ep, xmb, eb);
    fc_part<<<dim3(4, 8), 256, 0, stream>>>(eb, W_fc, fp);
    fc_red <<<dim3(4, NB), 256, 0, stream>>>(fp, b_fc, out);
    head_part<<<8, 64, 0, stream>>>(out, W_mu, W_sig, hp);
    head_red <<<NB, 64, 0, stream>>>(hp, b_mu, b_sig, out);
}